// Round 2
// baseline (8103.477 us; speedup 1.0000x reference)
//
#include <hip/hip_runtime.h>
#include <cstdint>
#include <cstddef>

// Problem constants (from reference setup_inputs)
#define N_NODES  50000
#define N_EDGES  800000
#define DIM_IN   128
#define DIM_H    512
#define N_GRAPHS 64
#define DIM_OUT  10
#define BN_EPS   1e-5f

typedef unsigned short u16;   // bf16 storage

__device__ inline float bf2f(u16 b) { return __uint_as_float(((unsigned)b) << 16); }
__device__ inline u16 f2bf(float f) {            // round-to-nearest-even
    unsigned u = __float_as_uint(f);
    u += 0x7FFFu + ((u >> 16) & 1u);
    return (u16)(u >> 16);
}
__device__ inline float tof(float v) { return v; }
__device__ inline float tof(u16 v)   { return bf2f(v); }

template<typename T> __device__ inline float4 load4f(const T* p);
template<> __device__ inline float4 load4f<float>(const float* p) {
    return *reinterpret_cast<const float4*>(p);
}
template<> __device__ inline float4 load4f<u16>(const u16* p) {
    ushort4 v = *reinterpret_cast<const ushort4*>(p);
    return make_float4(bf2f(v.x), bf2f(v.y), bf2f(v.z), bf2f(v.w));
}

// ---------------------------------------------------------------------------
// Edge aggregation (fp32 targets, fp32 atomics)
// ---------------------------------------------------------------------------
__global__ __launch_bounds__(256) void k_scatter128(
    const float4* __restrict__ X, const int* __restrict__ src,
    const int* __restrict__ dst, float* __restrict__ agg)
{
    int t = blockIdx.x * 256 + threadIdx.x;
    int e = t >> 5, lane = t & 31;          // 32 lanes/edge * float4 = 128 floats
    if (e >= N_EDGES) return;
    int s = src[e], d = dst[e];
    float4 v = X[(size_t)s * 32 + lane];
    float* p = agg + (size_t)d * 128 + lane * 4;
    atomicAdd(p + 0, v.x);
    atomicAdd(p + 1, v.y);
    atomicAdd(p + 2, v.z);
    atomicAdd(p + 3, v.w);
}

// tier A: full 512-wide scatter, fp32 source
__global__ __launch_bounds__(256) void k_scatter512(
    const float4* __restrict__ H, const int* __restrict__ src,
    const int* __restrict__ dst, float* __restrict__ agg)
{
    int t = blockIdx.x * 256 + threadIdx.x;
    int e = t >> 6, lane = t & 63;          // 64 lanes/edge, 2 float4 each
    if (e >= N_EDGES) return;
    int s = src[e], d = dst[e];
#pragma unroll
    for (int h = 0; h < 2; ++h) {
        int qd = lane + h * 64;             // 0..127 float4 within row
        float4 v = H[(size_t)s * 128 + qd];
        float* p = agg + (size_t)d * 512 + qd * 4;
        atomicAdd(p + 0, v.x);
        atomicAdd(p + 1, v.y);
        atomicAdd(p + 2, v.z);
        atomicAdd(p + 3, v.w);
    }
}

// tier B: 128-column chunk scatter from bf16 source into fp32 scratch
__global__ __launch_bounds__(256) void k_scatter_chunk(
    const u16* __restrict__ H, const int* __restrict__ src,
    const int* __restrict__ dst, int c0, float* __restrict__ F)
{
    int t = blockIdx.x * 256 + threadIdx.x;
    int e = t >> 5, lane = t & 31;
    if (e >= N_EDGES) return;
    int s = src[e], d = dst[e];
    float4 v = load4f<u16>(&H[(size_t)s * DIM_H + c0 + lane * 4]);
    float* p = F + (size_t)d * 128 + lane * 4;
    atomicAdd(p + 0, v.x);
    atomicAdd(p + 1, v.y);
    atomicAdd(p + 2, v.z);
    atomicAdd(p + 3, v.w);
}

// tier B: F[:, 0..127] = fp32(H[:, c0..c0+127])   (identity part of h + agg)
__global__ __launch_bounds__(256) void k_cvt_chunk(
    const u16* __restrict__ H, int c0, float* __restrict__ F)
{
    int t = blockIdx.x * 256 + threadIdx.x;
    if (t >= N_NODES * 32) return;
    int r = t >> 5, q = t & 31;
    float4 v = load4f<u16>(&H[(size_t)r * DIM_H + c0 + q * 4]);
    *reinterpret_cast<float4*>(&F[(size_t)r * 128 + q * 4]) = v;
}

// ---------------------------------------------------------------------------
// Tiled fp32-math GEMM: C[M,N] = op(A)[M,K] @ B[K,N] (+ bias | += )
//   TA: A storage type (float | u16 bf16); TC: C storage type
//   AFFINE: a -> relu(a*s[k]+c[k]) on load (folded BN+ReLU)
//   RELU: epilogue relu;  ACCUM: C += A@B (no bias)
// BM=BN=128, BK=16, 256 threads, 8x8 micro-tile per thread.
// ---------------------------------------------------------------------------
template<typename TA, typename TC, bool AFFINE, bool RELU, bool ACCUM>
__global__ __launch_bounds__(256) void k_gemm(
    const TA* __restrict__ A, const float* __restrict__ B,
    const float* __restrict__ bias, const float* __restrict__ sA,
    const float* __restrict__ cA, TC* __restrict__ C,
    int M, int N, int K, int lda)
{
    __shared__ float As[16][128];
    __shared__ float Bs[16][128];
    const int tid = threadIdx.x;
    const int tx = tid & 15;      // 16 col groups
    const int ty = tid >> 4;      // 16 row groups
    const int m0 = blockIdx.x * 128;
    const int n0 = blockIdx.y * 128;

    float acc[8][8] = {};

    for (int k0 = 0; k0 < K; k0 += 16) {
#pragma unroll
        for (int h = 0; h < 2; ++h) {
            int f = tid + h * 256;              // 0..511 quad slots
            // ---- A tile: [128 rows][16 k], one 4-wide load per slot
            int row = f >> 2, kq = f & 3;
            int ar = m0 + row; if (ar >= M) ar = M - 1;   // clamp (stores predicated)
            float4 v = load4f<TA>(&A[(size_t)ar * lda + k0 + kq * 4]);
            if (AFFINE) {
                int kk = k0 + kq * 4;
                float4 sv = *reinterpret_cast<const float4*>(&sA[kk]);
                float4 cv = *reinterpret_cast<const float4*>(&cA[kk]);
                v.x = fmaxf(fmaf(v.x, sv.x, cv.x), 0.f);
                v.y = fmaxf(fmaf(v.y, sv.y, cv.y), 0.f);
                v.z = fmaxf(fmaf(v.z, sv.z, cv.z), 0.f);
                v.w = fmaxf(fmaf(v.w, sv.w, cv.w), 0.f);
            }
            As[kq * 4 + 0][row] = v.x;
            As[kq * 4 + 1][row] = v.y;
            As[kq * 4 + 2][row] = v.z;
            As[kq * 4 + 3][row] = v.w;
            // ---- B tile: [16 k][128 n], one float4 (4 n) per slot
            int kr = f >> 5, nq = f & 31;
            *reinterpret_cast<float4*>(&Bs[kr][nq * 4]) =
                *reinterpret_cast<const float4*>(&B[(size_t)(k0 + kr) * N + n0 + nq * 4]);
        }
        __syncthreads();

#pragma unroll
        for (int k = 0; k < 16; ++k) {
            float ar_[8], br_[8];
            *reinterpret_cast<float4*>(&ar_[0]) = *reinterpret_cast<const float4*>(&As[k][ty * 8 + 0]);
            *reinterpret_cast<float4*>(&ar_[4]) = *reinterpret_cast<const float4*>(&As[k][ty * 8 + 4]);
            *reinterpret_cast<float4*>(&br_[0]) = *reinterpret_cast<const float4*>(&Bs[k][tx * 8 + 0]);
            *reinterpret_cast<float4*>(&br_[4]) = *reinterpret_cast<const float4*>(&Bs[k][tx * 8 + 4]);
#pragma unroll
            for (int i = 0; i < 8; ++i)
#pragma unroll
                for (int j = 0; j < 8; ++j)
                    acc[i][j] = fmaf(ar_[i], br_[j], acc[i][j]);
        }
        __syncthreads();
    }

    float bv[8];
    *reinterpret_cast<float4*>(&bv[0]) = *reinterpret_cast<const float4*>(&bias[n0 + tx * 8 + 0]);
    *reinterpret_cast<float4*>(&bv[4]) = *reinterpret_cast<const float4*>(&bias[n0 + tx * 8 + 4]);
#pragma unroll
    for (int i = 0; i < 8; ++i) {
        int row = m0 + ty * 8 + i;
        if (row >= M) continue;
        size_t off = (size_t)row * N + n0 + tx * 8;
        float o[8];
#pragma unroll
        for (int j = 0; j < 8; ++j) {
            float v = acc[i][j];
            if (!ACCUM) v += bv[j];
            o[j] = RELU ? fmaxf(v, 0.f) : v;
        }
        if constexpr (sizeof(TC) == 4) {
            float* Cp = (float*)C + off;
            if (ACCUM) {
                float4 e0 = *reinterpret_cast<float4*>(Cp);
                float4 e1 = *reinterpret_cast<float4*>(Cp + 4);
                o[0] += e0.x; o[1] += e0.y; o[2] += e0.z; o[3] += e0.w;
                o[4] += e1.x; o[5] += e1.y; o[6] += e1.z; o[7] += e1.w;
            }
            *reinterpret_cast<float4*>(Cp)     = make_float4(o[0], o[1], o[2], o[3]);
            *reinterpret_cast<float4*>(Cp + 4) = make_float4(o[4], o[5], o[6], o[7]);
        } else {
            u16* Cp = (u16*)C + off;
            if (ACCUM) {
                ushort4 e0 = *reinterpret_cast<ushort4*>(Cp);
                ushort4 e1 = *reinterpret_cast<ushort4*>(Cp + 4);
                o[0] += bf2f(e0.x); o[1] += bf2f(e0.y); o[2] += bf2f(e0.z); o[3] += bf2f(e0.w);
                o[4] += bf2f(e1.x); o[5] += bf2f(e1.y); o[6] += bf2f(e1.z); o[7] += bf2f(e1.w);
            }
            *reinterpret_cast<ushort4*>(Cp) =
                make_ushort4(f2bf(o[0]), f2bf(o[1]), f2bf(o[2]), f2bf(o[3]));
            *reinterpret_cast<ushort4*>(Cp + 4) =
                make_ushort4(f2bf(o[4]), f2bf(o[5]), f2bf(o[6]), f2bf(o[7]));
        }
    }
}

// ---------------------------------------------------------------------------
// Column statistics over T[N_NODES, 512]
// ---------------------------------------------------------------------------
template<typename T>
__global__ __launch_bounds__(256) void k_colstats(
    const T* __restrict__ Tm, float* __restrict__ csum, float* __restrict__ csq)
{
    int c = blockIdx.x * 256 + threadIdx.x;
    int nchunk = gridDim.y, chunk = blockIdx.y;
    int r0 = (int)(((long long)N_NODES * chunk) / nchunk);
    int r1 = (int)(((long long)N_NODES * (chunk + 1)) / nchunk);
    float s = 0.f, ss = 0.f;
    for (int r = r0; r < r1; ++r) {
        float v = tof(Tm[(size_t)r * DIM_H + c]);
        s += v;
        ss += v * v;
    }
    atomicAdd(&csum[c], s);
    atomicAdd(&csq[c], ss);
}

// Fold BN into per-column affine: s = g*rsqrt(var+eps), c = beta - mu*s
__global__ void k_fold(const float* __restrict__ csum, const float* __restrict__ csq,
                       const float* __restrict__ g, const float* __restrict__ be,
                       float* __restrict__ sf, float* __restrict__ cf)
{
    int c = threadIdx.x;   // 512
    const float invM = 1.0f / (float)N_NODES;
    float mu  = csum[c] * invM;
    float var = csq[c] * invM - mu * mu;
    float s   = g[c] * rsqrtf(var + BN_EPS);
    sf[c] = s;
    cf[c] = be[c] - mu * s;
}

// ---------------------------------------------------------------------------
// Graph pooling: batch sorted -> local accumulate, atomics at boundaries only
// ---------------------------------------------------------------------------
template<typename T>
__global__ __launch_bounds__(256) void k_pool(
    const T* __restrict__ H, const int* __restrict__ batch,
    float* __restrict__ pooled)
{
    __shared__ int bg[128];
    int base = blockIdx.x * 128;
    if (threadIdx.x < 128) {
        int r = base + threadIdx.x;
        bg[threadIdx.x] = (r < N_NODES) ? batch[r] : -1;
    }
    __syncthreads();
    int c0 = threadIdx.x;
    float a0 = 0.f, a1 = 0.f;
    int cur = bg[0];
    for (int r = 0; r < 128; ++r) {
        int g = bg[r];
        if (g < 0) break;
        if (g != cur) {
            atomicAdd(&pooled[cur * DIM_H + c0],       a0);
            atomicAdd(&pooled[cur * DIM_H + c0 + 256], a1);
            a0 = a1 = 0.f;
            cur = g;
        }
        size_t row = (size_t)(base + r);
        a0 += tof(H[row * DIM_H + c0]);
        a1 += tof(H[row * DIM_H + c0 + 256]);
    }
    if (cur >= 0) {
        atomicAdd(&pooled[cur * DIM_H + c0],       a0);
        atomicAdd(&pooled[cur * DIM_H + c0 + 256], a1);
    }
}

// head1: q[g] = relu(pooled[g] @ Wl1 + bl1)
__global__ __launch_bounds__(512) void k_head1(
    const float* __restrict__ pooled, const float* __restrict__ W,
    const float* __restrict__ b, float* __restrict__ q)
{
    __shared__ float row[DIM_H];
    int g = blockIdx.x, c = threadIdx.x;
    row[c] = pooled[(size_t)g * DIM_H + c];
    __syncthreads();
    float acc = 0.f;
    for (int k = 0; k < DIM_H; ++k)
        acc = fmaf(row[k], W[(size_t)k * DIM_H + c], acc);
    q[(size_t)g * DIM_H + c] = fmaxf(acc + b[c], 0.f);
}

// head2: out[g] = q[g] @ Wl2 + bl2
__global__ __launch_bounds__(256) void k_head2(
    const float* __restrict__ q, const float* __restrict__ W,
    const float* __restrict__ b, float* __restrict__ out)
{
    int t = blockIdx.x * 256 + threadIdx.x;
    if (t >= N_GRAPHS * DIM_OUT) return;
    int g = t / DIM_OUT, c = t % DIM_OUT;
    float acc = 0.f;
    for (int k = 0; k < DIM_H; ++k)
        acc = fmaf(q[(size_t)g * DIM_H + k], W[(size_t)k * DIM_OUT + c], acc);
    out[t] = acc + b[c];
}

// ---------------------------------------------------------------------------
extern "C" void kernel_launch(void* const* d_in, const int* in_sizes, int n_in,
                              void* d_out, int out_size, void* d_ws, size_t ws_size,
                              hipStream_t stream)
{
    const float* x   = (const float*)d_in[0];
    const int*   ei  = (const int*)d_in[1];
    const int*   src = ei;
    const int*   dst = ei + N_EDGES;
    const int*   batch = (const int*)d_in[2];
    const float* W1a = (const float*)d_in[3];
    const float* b1a = (const float*)d_in[4];
    const float* g1  = (const float*)d_in[5];
    const float* be1 = (const float*)d_in[6];
    const float* W1b = (const float*)d_in[7];
    const float* b1b = (const float*)d_in[8];
    const float* W2a = (const float*)d_in[9];
    const float* b2a = (const float*)d_in[10];
    const float* g2  = (const float*)d_in[11];
    const float* be2 = (const float*)d_in[12];
    const float* W2b = (const float*)d_in[13];
    const float* b2b = (const float*)d_in[14];
    const float* Wl1 = (const float*)d_in[15];
    const float* bl1 = (const float*)d_in[16];
    const float* Wl2 = (const float*)d_in[17];
    const float* bl2 = (const float*)d_in[18];

    char* ws = (char*)d_ws;
    const dim3 gemm_grid(391, 4);   // ceil(50000/128) x 512/128
    const size_t ROW_F = (size_t)N_NODES * DIM_H * 4;   // 102,400,000
    const size_t ROW_B = (size_t)N_NODES * DIM_H * 2;   //  51,200,000
    const size_t XA_F  = (size_t)N_NODES * DIM_IN * 4;  //  25,600,000

    if (ws_size >= 230700000ull) {
        // ================= Tier A: fp32 everywhere, buffer ping-pong ======
        float* B1 = (float*)(ws + 0);
        float* B2 = (float*)(ws + ROW_F);
        float* XA = (float*)(ws + 2 * ROW_F);
        char*  sm = ws + 2 * ROW_F + XA_F;
        float* csum   = (float*)(sm + 0);
        float* csq    = (float*)(sm + 2048);
        float* sf     = (float*)(sm + 4096);
        float* cf     = (float*)(sm + 6144);
        float* pooled = (float*)(sm + 8192);
        float* qbuf   = (float*)(sm + 8192 + 131072);

        // layer 1
        hipMemcpyAsync(XA, x, XA_F, hipMemcpyDeviceToDevice, stream);
        k_scatter128<<<(N_EDGES * 32) / 256, 256, 0, stream>>>(
            (const float4*)x, src, dst, XA);
        k_gemm<float, float, false, false, false><<<gemm_grid, 256, 0, stream>>>(
            XA, W1a, b1a, nullptr, nullptr, B1, N_NODES, DIM_H, DIM_IN, DIM_IN);
        hipMemsetAsync(csum, 0, 4096, stream);
        k_colstats<float><<<dim3(2, 128), 256, 0, stream>>>(B1, csum, csq);
        k_fold<<<1, 512, 0, stream>>>(csum, csq, g1, be1, sf, cf);
        k_gemm<float, float, true, true, false><<<gemm_grid, 256, 0, stream>>>(
            B1, W1b, b1b, sf, cf, B2, N_NODES, DIM_H, DIM_H, DIM_H);

        // layer 2
        hipMemcpyAsync(B1, B2, ROW_F, hipMemcpyDeviceToDevice, stream);
        k_scatter512<<<(N_EDGES * 64) / 256, 256, 0, stream>>>(
            (const float4*)B2, src, dst, B1);
        k_gemm<float, float, false, false, false><<<gemm_grid, 256, 0, stream>>>(
            B1, W2a, b2a, nullptr, nullptr, B2, N_NODES, DIM_H, DIM_H, DIM_H);
        hipMemsetAsync(csum, 0, 4096, stream);
        k_colstats<float><<<dim3(2, 128), 256, 0, stream>>>(B2, csum, csq);
        k_fold<<<1, 512, 0, stream>>>(csum, csq, g2, be2, sf, cf);
        k_gemm<float, float, true, true, false><<<gemm_grid, 256, 0, stream>>>(
            B2, W2b, b2b, sf, cf, B1, N_NODES, DIM_H, DIM_H, DIM_H);

        // pool + head
        hipMemsetAsync(pooled, 0, (size_t)N_GRAPHS * DIM_H * 4, stream);
        k_pool<float><<<(N_NODES + 127) / 128, 256, 0, stream>>>(B1, batch, pooled);
        k_head1<<<N_GRAPHS, 512, 0, stream>>>(pooled, Wl1, bl1, qbuf);
        k_head2<<<3, 256, 0, stream>>>(qbuf, Wl2, bl2, (float*)d_out);
    } else if (ws_size >= 128300000ull) {
        // ================= Tier B: bf16 node buffers, chunked layer-2 agg ==
        u16*   Bb1 = (u16*)(ws + 0);
        u16*   Bb2 = (u16*)(ws + ROW_B);
        float* F   = (float*)(ws + 2 * ROW_B);
        char*  sm  = ws + 2 * ROW_B + XA_F;
        float* csum   = (float*)(sm + 0);
        float* csq    = (float*)(sm + 2048);
        float* sf     = (float*)(sm + 4096);
        float* cf     = (float*)(sm + 6144);
        float* pooled = (float*)(sm + 8192);
        float* qbuf   = (float*)(sm + 8192 + 131072);

        // layer 1 (F = x + agg, fp32)
        hipMemcpyAsync(F, x, XA_F, hipMemcpyDeviceToDevice, stream);
        k_scatter128<<<(N_EDGES * 32) / 256, 256, 0, stream>>>(
            (const float4*)x, src, dst, F);
        k_gemm<float, u16, false, false, false><<<gemm_grid, 256, 0, stream>>>(
            F, W1a, b1a, nullptr, nullptr, Bb1, N_NODES, DIM_H, DIM_IN, DIM_IN);
        hipMemsetAsync(csum, 0, 4096, stream);
        k_colstats<u16><<<dim3(2, 128), 256, 0, stream>>>(Bb1, csum, csq);
        k_fold<<<1, 512, 0, stream>>>(csum, csq, g1, be1, sf, cf);
        k_gemm<u16, u16, true, true, false><<<gemm_grid, 256, 0, stream>>>(
            Bb1, W1b, b1b, sf, cf, Bb2, N_NODES, DIM_H, DIM_H, DIM_H);

        // layer 2: 4 x 128-column chunks through F, GEMM-accumulate into Bb1
        for (int c = 0; c < 4; ++c) {
            int c0 = c * 128;
            k_cvt_chunk<<<(N_NODES * 32) / 256 + 1, 256, 0, stream>>>(Bb2, c0, F);
            k_scatter_chunk<<<(N_EDGES * 32) / 256, 256, 0, stream>>>(
                Bb2, src, dst, c0, F);
            if (c == 0)
                k_gemm<float, u16, false, false, false><<<gemm_grid, 256, 0, stream>>>(
                    F, W2a + (size_t)c0 * DIM_H, b2a, nullptr, nullptr, Bb1,
                    N_NODES, DIM_H, 128, 128);
            else
                k_gemm<float, u16, false, false, true><<<gemm_grid, 256, 0, stream>>>(
                    F, W2a + (size_t)c0 * DIM_H, b2a, nullptr, nullptr, Bb1,
                    N_NODES, DIM_H, 128, 128);
        }
        hipMemsetAsync(csum, 0, 4096, stream);
        k_colstats<u16><<<dim3(2, 128), 256, 0, stream>>>(Bb1, csum, csq);
        k_fold<<<1, 512, 0, stream>>>(csum, csq, g2, be2, sf, cf);
        k_gemm<u16, u16, true, true, false><<<gemm_grid, 256, 0, stream>>>(
            Bb1, W2b, b2b, sf, cf, Bb2, N_NODES, DIM_H, DIM_H, DIM_H);

        // pool + head
        hipMemsetAsync(pooled, 0, (size_t)N_GRAPHS * DIM_H * 4, stream);
        k_pool<u16><<<(N_NODES + 127) / 128, 256, 0, stream>>>(Bb2, batch, pooled);
        k_head1<<<N_GRAPHS, 512, 0, stream>>>(pooled, Wl1, bl1, qbuf);
        k_head2<<<3, 256, 0, stream>>>(qbuf, Wl2, bl2, (float*)d_out);
    } else {
        // ws too small for any layout: emit zeros so the bench reports a clean
        // absmax failure (~350) instead of a GPU fault — diagnostic signal.
        hipMemsetAsync(d_out, 0, (size_t)out_size * 4, stream);
    }
}

// Round 4
// 1886.840 us; speedup vs baseline: 4.2947x; 4.2947x over previous
//
#include <hip/hip_runtime.h>
#include <cstdint>
#include <cstddef>

// Problem constants (from reference setup_inputs)
#define N_NODES  50000
#define N_EDGES  800000
#define DIM_IN   128
#define DIM_H    512
#define N_GRAPHS 64
#define DIM_OUT  10
#define BN_EPS   1e-5f

__device__ inline float4 add4(float4 a, float4 b) {
    return make_float4(a.x + b.x, a.y + b.y, a.z + b.z, a.w + b.w);
}

// ---------------------------------------------------------------------------
// CSR build: counting sort of edges by dst.
// ---------------------------------------------------------------------------
__global__ __launch_bounds__(256) void k_deg(
    const int* __restrict__ dst, int* __restrict__ deg)
{
    int t = blockIdx.x * 256 + threadIdx.x;
    if (t < N_EDGES) atomicAdd(&deg[dst[t]], 1);
}

// single-block exclusive scan of deg[0..N) -> rowptr[0..N], rowptr[N]=E
__global__ __launch_bounds__(1024) void k_scan(
    const int* __restrict__ deg, int* __restrict__ rowptr)
{
    __shared__ int part[1024];
    const int t = threadIdx.x;
    const int CH = (N_NODES + 1023) / 1024;   // 49
    const int base = t * CH;
    int s = 0;
    for (int i = 0; i < CH; ++i) {
        int idx = base + i;
        if (idx < N_NODES) s += deg[idx];
    }
    part[t] = s;
    __syncthreads();
    // Hillis-Steele inclusive scan over the 1024 partials
    for (int off = 1; off < 1024; off <<= 1) {
        int v = (t >= off) ? part[t - off] : 0;
        __syncthreads();
        part[t] += v;
        __syncthreads();
    }
    int run = (t == 0) ? 0 : part[t - 1];      // exclusive prefix of this chunk
    for (int i = 0; i < CH; ++i) {
        int idx = base + i;
        if (idx < N_NODES) {
            rowptr[idx] = run;
            run += deg[idx];
        } else if (idx == N_NODES) {
            rowptr[idx] = run;                 // == N_EDGES
        }
    }
}

// cursor starts as copy of rowptr[0..N); eidx[pos] = src for each edge
__global__ __launch_bounds__(256) void k_fill(
    const int* __restrict__ src, const int* __restrict__ dst,
    int* __restrict__ cursor, int* __restrict__ eidx)
{
    int t = blockIdx.x * 256 + threadIdx.x;
    if (t >= N_EDGES) return;
    int pos = atomicAdd(&cursor[dst[t]], 1);
    eidx[pos] = src[t];
}

// ---------------------------------------------------------------------------
// Gather aggregation: out[v] = X[v] + sum_{u in N_in(v)} X[u]
// 128-dim: 32 lanes/node, one float4 each.  512-dim: 64 lanes/node, 2 float4.
// ---------------------------------------------------------------------------
__global__ __launch_bounds__(256) void k_gather128(
    const float4* __restrict__ X, const int* __restrict__ rowptr,
    const int* __restrict__ eidx, float4* __restrict__ out)
{
    int t = blockIdx.x * 256 + threadIdx.x;
    int v = t >> 5, lane = t & 31;
    if (v >= N_NODES) return;
    int r0 = rowptr[v], r1 = rowptr[v + 1];
    float4 a = X[(size_t)v * 32 + lane];
    int j = r0;
    for (; j + 1 < r1; j += 2) {
        int s0 = eidx[j], s1 = eidx[j + 1];
        float4 b0 = X[(size_t)s0 * 32 + lane];
        float4 b1 = X[(size_t)s1 * 32 + lane];
        a = add4(a, add4(b0, b1));
    }
    if (j < r1) a = add4(a, X[(size_t)eidx[j] * 32 + lane]);
    out[(size_t)v * 32 + lane] = a;
}

__global__ __launch_bounds__(256) void k_gather512(
    const float4* __restrict__ X, const int* __restrict__ rowptr,
    const int* __restrict__ eidx, float4* __restrict__ out)
{
    int t = blockIdx.x * 256 + threadIdx.x;
    int v = t >> 6, lane = t & 63;
    if (v >= N_NODES) return;
    int r0 = rowptr[v], r1 = rowptr[v + 1];
    float4 a0 = X[(size_t)v * 128 + lane];
    float4 a1 = X[(size_t)v * 128 + lane + 64];
    for (int j = r0; j < r1; ++j) {
        int s = eidx[j];
        a0 = add4(a0, X[(size_t)s * 128 + lane]);
        a1 = add4(a1, X[(size_t)s * 128 + lane + 64]);
    }
    out[(size_t)v * 128 + lane]      = a0;
    out[(size_t)v * 128 + lane + 64] = a1;
}

// ---------------------------------------------------------------------------
// Tiled fp32 GEMM: C[M,N] = op(A)[M,K] @ B[K,N] + bias
//   AFFINE: a -> relu(a*s[k]+c[k]) on load (folded BN+ReLU)
//   RELU: epilogue relu
// BM=BN=128, BK=16, 256 threads, 8x8 micro-tile per thread.
// ---------------------------------------------------------------------------
template<bool AFFINE, bool RELU>
__global__ __launch_bounds__(256) void k_gemm(
    const float* __restrict__ A, const float* __restrict__ B,
    const float* __restrict__ bias, const float* __restrict__ sA,
    const float* __restrict__ cA, float* __restrict__ C,
    int M, int N, int K, int lda)
{
    __shared__ float As[16][128];
    __shared__ float Bs[16][128];
    const int tid = threadIdx.x;
    const int tx = tid & 15;
    const int ty = tid >> 4;
    const int m0 = blockIdx.x * 128;
    const int n0 = blockIdx.y * 128;

    float acc[8][8] = {};

    for (int k0 = 0; k0 < K; k0 += 16) {
#pragma unroll
        for (int h = 0; h < 2; ++h) {
            int f = tid + h * 256;
            int row = f >> 2, kq = f & 3;
            int ar = m0 + row; if (ar >= M) ar = M - 1;   // clamp (stores predicated)
            float4 v = *reinterpret_cast<const float4*>(&A[(size_t)ar * lda + k0 + kq * 4]);
            if (AFFINE) {
                int kk = k0 + kq * 4;
                float4 sv = *reinterpret_cast<const float4*>(&sA[kk]);
                float4 cv = *reinterpret_cast<const float4*>(&cA[kk]);
                v.x = fmaxf(fmaf(v.x, sv.x, cv.x), 0.f);
                v.y = fmaxf(fmaf(v.y, sv.y, cv.y), 0.f);
                v.z = fmaxf(fmaf(v.z, sv.z, cv.z), 0.f);
                v.w = fmaxf(fmaf(v.w, sv.w, cv.w), 0.f);
            }
            As[kq * 4 + 0][row] = v.x;
            As[kq * 4 + 1][row] = v.y;
            As[kq * 4 + 2][row] = v.z;
            As[kq * 4 + 3][row] = v.w;
            int kr = f >> 5, nq = f & 31;
            *reinterpret_cast<float4*>(&Bs[kr][nq * 4]) =
                *reinterpret_cast<const float4*>(&B[(size_t)(k0 + kr) * N + n0 + nq * 4]);
        }
        __syncthreads();

#pragma unroll
        for (int k = 0; k < 16; ++k) {
            float ar_[8], br_[8];
            *reinterpret_cast<float4*>(&ar_[0]) = *reinterpret_cast<const float4*>(&As[k][ty * 8 + 0]);
            *reinterpret_cast<float4*>(&ar_[4]) = *reinterpret_cast<const float4*>(&As[k][ty * 8 + 4]);
            *reinterpret_cast<float4*>(&br_[0]) = *reinterpret_cast<const float4*>(&Bs[k][tx * 8 + 0]);
            *reinterpret_cast<float4*>(&br_[4]) = *reinterpret_cast<const float4*>(&Bs[k][tx * 8 + 4]);
#pragma unroll
            for (int i = 0; i < 8; ++i)
#pragma unroll
                for (int j = 0; j < 8; ++j)
                    acc[i][j] = fmaf(ar_[i], br_[j], acc[i][j]);
        }
        __syncthreads();
    }

    float bv[8];
    *reinterpret_cast<float4*>(&bv[0]) = *reinterpret_cast<const float4*>(&bias[n0 + tx * 8 + 0]);
    *reinterpret_cast<float4*>(&bv[4]) = *reinterpret_cast<const float4*>(&bias[n0 + tx * 8 + 4]);
#pragma unroll
    for (int i = 0; i < 8; ++i) {
        int row = m0 + ty * 8 + i;
        if (row >= M) continue;
        float o[8];
#pragma unroll
        for (int j = 0; j < 8; ++j) {
            float v = acc[i][j] + bv[j];
            o[j] = RELU ? fmaxf(v, 0.f) : v;
        }
        *reinterpret_cast<float4*>(&C[(size_t)row * N + n0 + tx * 8 + 0]) = *reinterpret_cast<float4*>(&o[0]);
        *reinterpret_cast<float4*>(&C[(size_t)row * N + n0 + tx * 8 + 4]) = *reinterpret_cast<float4*>(&o[4]);
    }
}

// ---------------------------------------------------------------------------
// Column statistics over T[N_NODES, 512]: per-column sum and sum-of-squares
// ---------------------------------------------------------------------------
__global__ __launch_bounds__(256) void k_colstats(
    const float* __restrict__ T, float* __restrict__ csum, float* __restrict__ csq)
{
    int c = blockIdx.x * 256 + threadIdx.x;
    int nchunk = gridDim.y, chunk = blockIdx.y;
    int r0 = (int)(((long long)N_NODES * chunk) / nchunk);
    int r1 = (int)(((long long)N_NODES * (chunk + 1)) / nchunk);
    float s = 0.f, ss = 0.f;
    for (int r = r0; r < r1; ++r) {
        float v = T[(size_t)r * DIM_H + c];
        s += v;
        ss += v * v;
    }
    atomicAdd(&csum[c], s);
    atomicAdd(&csq[c], ss);
}

// Fold BN into per-column affine: s = g*rsqrt(var+eps), c = beta - mu*s
__global__ void k_fold(const float* __restrict__ csum, const float* __restrict__ csq,
                       const float* __restrict__ g, const float* __restrict__ be,
                       float* __restrict__ sf, float* __restrict__ cf)
{
    int c = threadIdx.x;   // 512
    const float invM = 1.0f / (float)N_NODES;
    float mu  = csum[c] * invM;
    float var = csq[c] * invM - mu * mu;
    float s   = g[c] * rsqrtf(var + BN_EPS);
    sf[c] = s;
    cf[c] = be[c] - mu * s;
}

// ---------------------------------------------------------------------------
// Graph pooling: batch sorted -> local accumulate, atomics at boundaries only
// ---------------------------------------------------------------------------
__global__ __launch_bounds__(256) void k_pool(
    const float* __restrict__ H, const int* __restrict__ batch,
    float* __restrict__ pooled)
{
    __shared__ int bg[128];
    int base = blockIdx.x * 128;
    if (threadIdx.x < 128) {
        int r = base + threadIdx.x;
        bg[threadIdx.x] = (r < N_NODES) ? batch[r] : -1;
    }
    __syncthreads();
    int c0 = threadIdx.x;
    float a0 = 0.f, a1 = 0.f;
    int cur = bg[0];
    for (int r = 0; r < 128; ++r) {
        int g = bg[r];
        if (g < 0) break;
        if (g != cur) {
            atomicAdd(&pooled[cur * DIM_H + c0],       a0);
            atomicAdd(&pooled[cur * DIM_H + c0 + 256], a1);
            a0 = a1 = 0.f;
            cur = g;
        }
        size_t row = (size_t)(base + r);
        a0 += H[row * DIM_H + c0];
        a1 += H[row * DIM_H + c0 + 256];
    }
    if (cur >= 0) {
        atomicAdd(&pooled[cur * DIM_H + c0],       a0);
        atomicAdd(&pooled[cur * DIM_H + c0 + 256], a1);
    }
}

// head1: q[g] = relu(pooled[g] @ Wl1 + bl1)
__global__ __launch_bounds__(512) void k_head1(
    const float* __restrict__ pooled, const float* __restrict__ W,
    const float* __restrict__ b, float* __restrict__ q)
{
    __shared__ float row[DIM_H];
    int g = blockIdx.x, c = threadIdx.x;
    row[c] = pooled[(size_t)g * DIM_H + c];
    __syncthreads();
    float acc = 0.f;
    for (int k = 0; k < DIM_H; ++k)
        acc = fmaf(row[k], W[(size_t)k * DIM_H + c], acc);
    q[(size_t)g * DIM_H + c] = fmaxf(acc + b[c], 0.f);
}

// head2: out[g] = q[g] @ Wl2 + bl2
__global__ __launch_bounds__(256) void k_head2(
    const float* __restrict__ q, const float* __restrict__ W,
    const float* __restrict__ b, float* __restrict__ out)
{
    int t = blockIdx.x * 256 + threadIdx.x;
    if (t >= N_GRAPHS * DIM_OUT) return;
    int g = t / DIM_OUT, c = t % DIM_OUT;
    float acc = 0.f;
    for (int k = 0; k < DIM_H; ++k)
        acc = fmaf(q[(size_t)g * DIM_H + k], W[(size_t)k * DIM_OUT + c], acc);
    out[t] = acc + b[c];
}

// ---------------------------------------------------------------------------
extern "C" void kernel_launch(void* const* d_in, const int* in_sizes, int n_in,
                              void* d_out, int out_size, void* d_ws, size_t ws_size,
                              hipStream_t stream)
{
    const float* x   = (const float*)d_in[0];
    const int*   ei  = (const int*)d_in[1];
    const int*   src = ei;
    const int*   dst = ei + N_EDGES;
    const int*   batch = (const int*)d_in[2];
    const float* W1a = (const float*)d_in[3];
    const float* b1a = (const float*)d_in[4];
    const float* g1  = (const float*)d_in[5];
    const float* be1 = (const float*)d_in[6];
    const float* W1b = (const float*)d_in[7];
    const float* b1b = (const float*)d_in[8];
    const float* W2a = (const float*)d_in[9];
    const float* b2a = (const float*)d_in[10];
    const float* g2  = (const float*)d_in[11];
    const float* be2 = (const float*)d_in[12];
    const float* W2b = (const float*)d_in[13];
    const float* b2b = (const float*)d_in[14];
    const float* Wl1 = (const float*)d_in[15];
    const float* bl1 = (const float*)d_in[16];
    const float* Wl2 = (const float*)d_in[17];
    const float* bl2 = (const float*)d_in[18];

    char* ws = (char*)d_ws;
    const size_t ROW_F = (size_t)N_NODES * DIM_H * 4;   // 102,400,000

    // Layout (~208.9 MB total; bench R2 confirmed ws >= 230.7 MB):
    //   B1 @ 0, B2 @ ROW_F (XA aliases front of B2), CSR + stats after.
    if (ws_size < 208900000ull) {
        hipMemsetAsync(d_out, 0, (size_t)out_size * 4, stream);
        return;
    }
    float* B1 = (float*)(ws + 0);
    float* B2 = (float*)(ws + ROW_F);
    float* XA = B2;                                   // 25.6 MB, dead after GEMM1
    char*  cp = ws + 2 * ROW_F;                       // 204,800,000
    int* deg    = (int*)(cp + 0);                     // 200,000 -> pad 200,192
    int* rowptr = (int*)(cp + 200192);                // 200,004 -> pad 200,192
    int* cursor = (int*)(cp + 400384);                // 200,000 -> pad 200,192
    int* eidx   = (int*)(cp + 600576);                // 3,200,000
    char* sm    = cp + 3800576;
    float* csum   = (float*)(sm + 0);
    float* csq    = (float*)(sm + 2048);
    float* sf     = (float*)(sm + 4096);
    float* cf     = (float*)(sm + 6144);
    float* pooled = (float*)(sm + 8192);
    float* qbuf   = (float*)(sm + 8192 + 131072);

    const dim3 gemm_grid(391, 4);   // ceil(50000/128) x 512/128
    const int EB = (N_EDGES + 255) / 256;

    // ---- CSR build (counting sort by dst) ----
    hipMemsetAsync(deg, 0, (size_t)N_NODES * 4, stream);
    k_deg<<<EB, 256, 0, stream>>>(dst, deg);
    k_scan<<<1, 1024, 0, stream>>>(deg, rowptr);
    hipMemcpyAsync(cursor, rowptr, (size_t)N_NODES * 4, hipMemcpyDeviceToDevice, stream);
    k_fill<<<EB, 256, 0, stream>>>(src, dst, cursor, eidx);

    // ---- layer 1 ----
    k_gather128<<<(N_NODES * 32) / 256, 256, 0, stream>>>(
        (const float4*)x, rowptr, eidx, (float4*)XA);
    k_gemm<false, false><<<gemm_grid, 256, 0, stream>>>(
        XA, W1a, b1a, nullptr, nullptr, B1, N_NODES, DIM_H, DIM_IN, DIM_IN);
    hipMemsetAsync(csum, 0, 4096, stream);
    k_colstats<<<dim3(2, 128), 256, 0, stream>>>(B1, csum, csq);
    k_fold<<<1, 512, 0, stream>>>(csum, csq, g1, be1, sf, cf);
    k_gemm<true, true><<<gemm_grid, 256, 0, stream>>>(
        B1, W1b, b1b, sf, cf, B2, N_NODES, DIM_H, DIM_H, DIM_H);

    // ---- layer 2 ----
    k_gather512<<<(N_NODES * 64) / 256, 256, 0, stream>>>(
        (const float4*)B2, rowptr, eidx, (float4*)B1);
    k_gemm<false, false><<<gemm_grid, 256, 0, stream>>>(
        B1, W2a, b2a, nullptr, nullptr, B2, N_NODES, DIM_H, DIM_H, DIM_H);
    hipMemsetAsync(csum, 0, 4096, stream);
    k_colstats<<<dim3(2, 128), 256, 0, stream>>>(B2, csum, csq);
    k_fold<<<1, 512, 0, stream>>>(csum, csq, g2, be2, sf, cf);
    k_gemm<true, true><<<gemm_grid, 256, 0, stream>>>(
        B2, W2b, b2b, sf, cf, B1, N_NODES, DIM_H, DIM_H, DIM_H);

    // ---- pool + head ----
    hipMemsetAsync(pooled, 0, (size_t)N_GRAPHS * DIM_H * 4, stream);
    k_pool<<<(N_NODES + 127) / 128, 256, 0, stream>>>(B1, batch, pooled);
    k_head1<<<N_GRAPHS, 512, 0, stream>>>(pooled, Wl1, bl1, qbuf);
    k_head2<<<3, 256, 0, stream>>>(qbuf, Wl2, bl2, (float*)d_out);
}

// Round 8
// 1051.855 us; speedup vs baseline: 7.7040x; 1.7938x over previous
//
#include <hip/hip_runtime.h>
#include <cstdint>
#include <cstddef>

// Problem constants (from reference setup_inputs)
#define N_NODES  50000
#define N_EDGES  800000
#define DIM_IN   128
#define DIM_H    512
#define N_GRAPHS 64
#define DIM_OUT  10
#define BN_EPS   1e-5f

using f16x8 = __attribute__((ext_vector_type(8))) _Float16;
using f32x4 = __attribute__((ext_vector_type(4))) float;

__device__ inline float4 add4(float4 a, float4 b) {
    return make_float4(a.x + b.x, a.y + b.y, a.z + b.z, a.w + b.w);
}

// ---------------------------------------------------------------------------
// CSR build: counting sort of edges by dst.
// ---------------------------------------------------------------------------
__global__ __launch_bounds__(256) void k_deg(
    const int* __restrict__ dst, int* __restrict__ deg)
{
    int t = blockIdx.x * 256 + threadIdx.x;
    if (t < N_EDGES) atomicAdd(&deg[dst[t]], 1);
}

// single-block exclusive scan of deg[0..N) -> rowptr[0..N], rowptr[N]=E
__global__ __launch_bounds__(1024) void k_scan(
    const int* __restrict__ deg, int* __restrict__ rowptr)
{
    __shared__ int part[1024];
    const int t = threadIdx.x;
    const int CH = (N_NODES + 1023) / 1024;   // 49
    const int base = t * CH;
    int s = 0;
    for (int i = 0; i < CH; ++i) {
        int idx = base + i;
        if (idx < N_NODES) s += deg[idx];
    }
    part[t] = s;
    __syncthreads();
    for (int off = 1; off < 1024; off <<= 1) {
        int v = (t >= off) ? part[t - off] : 0;
        __syncthreads();
        part[t] += v;
        __syncthreads();
    }
    int run = (t == 0) ? 0 : part[t - 1];
    for (int i = 0; i < CH; ++i) {
        int idx = base + i;
        if (idx < N_NODES) {
            rowptr[idx] = run;
            run += deg[idx];
        } else if (idx == N_NODES) {
            rowptr[idx] = run;                 // == N_EDGES
        }
    }
}

// cursor starts as copy of rowptr[0..N); eidx[pos] = src for each edge
__global__ __launch_bounds__(256) void k_fill(
    const int* __restrict__ src, const int* __restrict__ dst,
    int* __restrict__ cursor, int* __restrict__ eidx)
{
    int t = blockIdx.x * 256 + threadIdx.x;
    if (t >= N_EDGES) return;
    int pos = atomicAdd(&cursor[dst[t]], 1);
    eidx[pos] = src[t];
}

// ---------------------------------------------------------------------------
// Gather aggregation: out[v] = X[v] + sum_{u in N_in(v)} X[u]
// ---------------------------------------------------------------------------
__global__ __launch_bounds__(256) void k_gather128(
    const float4* __restrict__ X, const int* __restrict__ rowptr,
    const int* __restrict__ eidx, float4* __restrict__ out)
{
    int t = blockIdx.x * 256 + threadIdx.x;
    int v = t >> 5, lane = t & 31;
    if (v >= N_NODES) return;
    int r0 = rowptr[v], r1 = rowptr[v + 1];
    float4 a = X[(size_t)v * 32 + lane];
    int j = r0;
    for (; j + 1 < r1; j += 2) {
        int s0 = eidx[j], s1 = eidx[j + 1];
        float4 b0 = X[(size_t)s0 * 32 + lane];
        float4 b1 = X[(size_t)s1 * 32 + lane];
        a = add4(a, add4(b0, b1));
    }
    if (j < r1) a = add4(a, X[(size_t)eidx[j] * 32 + lane]);
    out[(size_t)v * 32 + lane] = a;
}

__global__ __launch_bounds__(256) void k_gather512(
    const float4* __restrict__ X, const int* __restrict__ rowptr,
    const int* __restrict__ eidx, float4* __restrict__ out)
{
    int t = blockIdx.x * 256 + threadIdx.x;
    int v = t >> 6, lane = t & 63;
    if (v >= N_NODES) return;
    int r0 = rowptr[v], r1 = rowptr[v + 1];
    float4 a0 = X[(size_t)v * 128 + lane];
    float4 a1 = X[(size_t)v * 128 + lane + 64];
    for (int j = r0; j < r1; ++j) {
        int s = eidx[j];
        a0 = add4(a0, X[(size_t)s * 128 + lane]);
        a1 = add4(a1, X[(size_t)s * 128 + lane + 64]);
    }
    out[(size_t)v * 128 + lane]      = a0;
    out[(size_t)v * 128 + lane + 64] = a1;
}

// ---------------------------------------------------------------------------
// MFMA GEMM (fp16 operands, fp32 accumulate): C[M,N] = op(A) @ B + bias
//   AFFINE: a -> relu(a*s[k]+c[k]) on A load (folded BN+ReLU)
//   RELU: epilogue relu
// BM=128, BN=256, BK=32. 512 threads = 8 waves (2x4), wave tile 64x64,
// 4x4 fragments of v_mfma_f32_16x16x32_f16.
// Fragment maps (gfx950, learn_hip m89-verified family):
//   A: lane l holds A[l&15][8*(l>>4)+j], j=0..7
//   B: lane l holds B[8*(l>>4)+j][l&15]
//   D: lane l reg r holds D[4*(l>>4)+r][l&15]
// LDS: As[kb][row][8] / Bs[kb][col][8] -> frag read = one ds_read_b128.
// ---------------------------------------------------------------------------
template<bool AFFINE, bool RELU>
__global__ __launch_bounds__(512) void k_gemm_mfma(
    const float* __restrict__ A, const float* __restrict__ B,
    const float* __restrict__ bias, const float* __restrict__ sA,
    const float* __restrict__ cA, float* __restrict__ C,
    int M, int N, int K, int lda)
{
    __shared__ _Float16 As[4][128][8];   //  8 KB
    __shared__ _Float16 Bs[4][256][8];   // 16 KB

    const int tid  = threadIdx.x;
    const int lane = tid & 63;
    const int w    = tid >> 6;          // 0..7
    const int wr   = w >> 2;            // 0..1 (row half)
    const int wc   = w & 3;             // 0..3 (col quarter)
    const int l15  = lane & 15;
    const int lk   = lane >> 4;         // k-group 0..3
    const int m0   = blockIdx.x * 128;
    const int n0   = blockIdx.y * 256;

    // A staging: one (row, kb) entry per thread
    const int s_row = tid >> 2;         // 0..127
    const int s_kb  = tid & 3;          // 0..3
    int ar = m0 + s_row; if (ar >= M) ar = M - 1;     // clamp; stores predicated
    const float* aptr = A + (size_t)ar * lda + s_kb * 8;

    f32x4 acc[4][4];
#pragma unroll
    for (int m = 0; m < 4; ++m)
#pragma unroll
        for (int n = 0; n < 4; ++n)
            acc[m][n] = (f32x4){0.f, 0.f, 0.f, 0.f};

    for (int k0 = 0; k0 < K; k0 += 32) {
        // ---- global loads (regs) ----
        float4 a0 = *reinterpret_cast<const float4*>(aptr + k0);
        float4 a1 = *reinterpret_cast<const float4*>(aptr + k0 + 4);
        if (AFFINE) {
            int kk = k0 + s_kb * 8;
            float4 s0 = *reinterpret_cast<const float4*>(&sA[kk]);
            float4 s1 = *reinterpret_cast<const float4*>(&sA[kk + 4]);
            float4 c0 = *reinterpret_cast<const float4*>(&cA[kk]);
            float4 c1 = *reinterpret_cast<const float4*>(&cA[kk + 4]);
            a0.x = fmaxf(fmaf(a0.x, s0.x, c0.x), 0.f);
            a0.y = fmaxf(fmaf(a0.y, s0.y, c0.y), 0.f);
            a0.z = fmaxf(fmaf(a0.z, s0.z, c0.z), 0.f);
            a0.w = fmaxf(fmaf(a0.w, s0.w, c0.w), 0.f);
            a1.x = fmaxf(fmaf(a1.x, s1.x, c1.x), 0.f);
            a1.y = fmaxf(fmaf(a1.y, s1.y, c1.y), 0.f);
            a1.z = fmaxf(fmaf(a1.z, s1.z, c1.z), 0.f);
            a1.w = fmaxf(fmaf(a1.w, s1.w, c1.w), 0.f);
        }
        f16x8 av;
        av[0] = (_Float16)a0.x; av[1] = (_Float16)a0.y;
        av[2] = (_Float16)a0.z; av[3] = (_Float16)a0.w;
        av[4] = (_Float16)a1.x; av[5] = (_Float16)a1.y;
        av[6] = (_Float16)a1.z; av[7] = (_Float16)a1.w;

        float bv[2][8];
#pragma unroll
        for (int h = 0; h < 2; ++h) {
            int idx = tid + h * 512;
            int kb = idx >> 8, nc = idx & 255;
            const float* bp = B + (size_t)(k0 + kb * 8) * N + n0 + nc;
#pragma unroll
            for (int j = 0; j < 8; ++j)
                bv[h][j] = bp[(size_t)j * N];
        }

        __syncthreads();   // previous tile fully consumed
        *reinterpret_cast<f16x8*>(&As[s_kb][s_row][0]) = av;
#pragma unroll
        for (int h = 0; h < 2; ++h) {
            int idx = tid + h * 512;
            int kb = idx >> 8, nc = idx & 255;
            f16x8 bw;
#pragma unroll
            for (int j = 0; j < 8; ++j) bw[j] = (_Float16)bv[h][j];
            *reinterpret_cast<f16x8*>(&Bs[kb][nc][0]) = bw;
        }
        __syncthreads();   // tile ready

        // ---- MFMA: 16 per wave ----
        f16x8 af[4], bf[4];
#pragma unroll
        for (int m = 0; m < 4; ++m)
            af[m] = *reinterpret_cast<const f16x8*>(&As[lk][wr * 64 + m * 16 + l15][0]);
#pragma unroll
        for (int n = 0; n < 4; ++n)
            bf[n] = *reinterpret_cast<const f16x8*>(&Bs[lk][wc * 64 + n * 16 + l15][0]);
#pragma unroll
        for (int m = 0; m < 4; ++m)
#pragma unroll
            for (int n = 0; n < 4; ++n)
                acc[m][n] = __builtin_amdgcn_mfma_f32_16x16x32_f16(
                    af[m], bf[n], acc[m][n], 0, 0, 0);
    }

    // ---- epilogue ----
#pragma unroll
    for (int n = 0; n < 4; ++n) {
        int col = n0 + wc * 64 + n * 16 + l15;
        float bb = bias[col];
#pragma unroll
        for (int m = 0; m < 4; ++m) {
            int row0 = m0 + wr * 64 + m * 16 + lk * 4;
#pragma unroll
            for (int r = 0; r < 4; ++r) {
                int row = row0 + r;
                if (row < M) {
                    float v = acc[m][n][r] + bb;
                    if (RELU) v = fmaxf(v, 0.f);
                    C[(size_t)row * N + col] = v;
                }
            }
        }
    }
}

// ---------------------------------------------------------------------------
// Column statistics over T[N_NODES, 512]: per-column sum and sum-of-squares
// ---------------------------------------------------------------------------
__global__ __launch_bounds__(256) void k_colstats(
    const float* __restrict__ T, float* __restrict__ csum, float* __restrict__ csq)
{
    int c = blockIdx.x * 256 + threadIdx.x;
    int nchunk = gridDim.y, chunk = blockIdx.y;
    int r0 = (int)(((long long)N_NODES * chunk) / nchunk);
    int r1 = (int)(((long long)N_NODES * (chunk + 1)) / nchunk);
    float s = 0.f, ss = 0.f;
    for (int r = r0; r < r1; ++r) {
        float v = T[(size_t)r * DIM_H + c];
        s += v;
        ss += v * v;
    }
    atomicAdd(&csum[c], s);
    atomicAdd(&csq[c], ss);
}

// Fold BN into per-column affine: s = g*rsqrt(var+eps), c = beta - mu*s
__global__ void k_fold(const float* __restrict__ csum, const float* __restrict__ csq,
                       const float* __restrict__ g, const float* __restrict__ be,
                       float* __restrict__ sf, float* __restrict__ cf)
{
    int c = threadIdx.x;   // 512
    const float invM = 1.0f / (float)N_NODES;
    float mu  = csum[c] * invM;
    float var = csq[c] * invM - mu * mu;
    float s   = g[c] * rsqrtf(var + BN_EPS);
    sf[c] = s;
    cf[c] = be[c] - mu * s;
}

// ---------------------------------------------------------------------------
// Graph pooling: batch sorted -> local accumulate, atomics at boundaries only
// ---------------------------------------------------------------------------
__global__ __launch_bounds__(256) void k_pool(
    const float* __restrict__ H, const int* __restrict__ batch,
    float* __restrict__ pooled)
{
    __shared__ int bg[128];
    int base = blockIdx.x * 128;
    if (threadIdx.x < 128) {
        int r = base + threadIdx.x;
        bg[threadIdx.x] = (r < N_NODES) ? batch[r] : -1;
    }
    __syncthreads();
    int c0 = threadIdx.x;
    float a0 = 0.f, a1 = 0.f;
    int cur = bg[0];
    for (int r = 0; r < 128; ++r) {
        int g = bg[r];
        if (g < 0) break;
        if (g != cur) {
            atomicAdd(&pooled[cur * DIM_H + c0],       a0);
            atomicAdd(&pooled[cur * DIM_H + c0 + 256], a1);
            a0 = a1 = 0.f;
            cur = g;
        }
        size_t row = (size_t)(base + r);
        a0 += H[row * DIM_H + c0];
        a1 += H[row * DIM_H + c0 + 256];
    }
    if (cur >= 0) {
        atomicAdd(&pooled[cur * DIM_H + c0],       a0);
        atomicAdd(&pooled[cur * DIM_H + c0 + 256], a1);
    }
}

// head1: q[g] = relu(pooled[g] @ Wl1 + bl1)
__global__ __launch_bounds__(512) void k_head1(
    const float* __restrict__ pooled, const float* __restrict__ W,
    const float* __restrict__ b, float* __restrict__ q)
{
    __shared__ float row[DIM_H];
    int g = blockIdx.x, c = threadIdx.x;
    row[c] = pooled[(size_t)g * DIM_H + c];
    __syncthreads();
    float acc = 0.f;
    for (int k = 0; k < DIM_H; ++k)
        acc = fmaf(row[k], W[(size_t)k * DIM_H + c], acc);
    q[(size_t)g * DIM_H + c] = fmaxf(acc + b[c], 0.f);
}

// head2: out[g] = q[g] @ Wl2 + bl2
__global__ __launch_bounds__(256) void k_head2(
    const float* __restrict__ q, const float* __restrict__ W,
    const float* __restrict__ b, float* __restrict__ out)
{
    int t = blockIdx.x * 256 + threadIdx.x;
    if (t >= N_GRAPHS * DIM_OUT) return;
    int g = t / DIM_OUT, c = t % DIM_OUT;
    float acc = 0.f;
    for (int k = 0; k < DIM_H; ++k)
        acc = fmaf(q[(size_t)g * DIM_H + k], W[(size_t)k * DIM_OUT + c], acc);
    out[t] = acc + b[c];
}

// ---------------------------------------------------------------------------
extern "C" void kernel_launch(void* const* d_in, const int* in_sizes, int n_in,
                              void* d_out, int out_size, void* d_ws, size_t ws_size,
                              hipStream_t stream)
{
    const float* x   = (const float*)d_in[0];
    const int*   ei  = (const int*)d_in[1];
    const int*   src = ei;
    const int*   dst = ei + N_EDGES;
    const int*   batch = (const int*)d_in[2];
    const float* W1a = (const float*)d_in[3];
    const float* b1a = (const float*)d_in[4];
    const float* g1  = (const float*)d_in[5];
    const float* be1 = (const float*)d_in[6];
    const float* W1b = (const float*)d_in[7];
    const float* b1b = (const float*)d_in[8];
    const float* W2a = (const float*)d_in[9];
    const float* b2a = (const float*)d_in[10];
    const float* g2  = (const float*)d_in[11];
    const float* be2 = (const float*)d_in[12];
    const float* W2b = (const float*)d_in[13];
    const float* b2b = (const float*)d_in[14];
    const float* Wl1 = (const float*)d_in[15];
    const float* bl1 = (const float*)d_in[16];
    const float* Wl2 = (const float*)d_in[17];
    const float* bl2 = (const float*)d_in[18];

    char* ws = (char*)d_ws;
    const size_t ROW_F = (size_t)N_NODES * DIM_H * 4;   // 102,400,000

    if (ws_size < 208900000ull) {
        hipMemsetAsync(d_out, 0, (size_t)out_size * 4, stream);
        return;
    }
    float* B1 = (float*)(ws + 0);
    float* B2 = (float*)(ws + ROW_F);
    float* XA = B2;                                   // 25.6 MB, dead after GEMM1
    char*  cp = ws + 2 * ROW_F;                       // 204,800,000
    int* deg    = (int*)(cp + 0);
    int* rowptr = (int*)(cp + 200192);
    int* cursor = (int*)(cp + 400384);
    int* eidx   = (int*)(cp + 600576);
    char* sm    = cp + 3800576;
    float* csum   = (float*)(sm + 0);
    float* csq    = (float*)(sm + 2048);
    float* sf     = (float*)(sm + 4096);
    float* cf     = (float*)(sm + 6144);
    float* pooled = (float*)(sm + 8192);
    float* qbuf   = (float*)(sm + 8192 + 131072);

    const dim3 gemm_grid(391, 2);   // ceil(50000/128) x 512/256
    const int EB = (N_EDGES + 255) / 256;

    // ---- CSR build (counting sort by dst) ----
    hipMemsetAsync(deg, 0, (size_t)N_NODES * 4, stream);
    k_deg<<<EB, 256, 0, stream>>>(dst, deg);
    k_scan<<<1, 1024, 0, stream>>>(deg, rowptr);
    hipMemcpyAsync(cursor, rowptr, (size_t)N_NODES * 4, hipMemcpyDeviceToDevice, stream);
    k_fill<<<EB, 256, 0, stream>>>(src, dst, cursor, eidx);

    // ---- layer 1 ----
    k_gather128<<<(N_NODES * 32) / 256, 256, 0, stream>>>(
        (const float4*)x, rowptr, eidx, (float4*)XA);
    k_gemm_mfma<false, false><<<gemm_grid, 512, 0, stream>>>(
        XA, W1a, b1a, nullptr, nullptr, B1, N_NODES, DIM_H, DIM_IN, DIM_IN);
    hipMemsetAsync(csum, 0, 4096, stream);
    k_colstats<<<dim3(2, 128), 256, 0, stream>>>(B1, csum, csq);
    k_fold<<<1, 512, 0, stream>>>(csum, csq, g1, be1, sf, cf);
    k_gemm_mfma<true, true><<<gemm_grid, 512, 0, stream>>>(
        B1, W1b, b1b, sf, cf, B2, N_NODES, DIM_H, DIM_H, DIM_H);

    // ---- layer 2 ----
    k_gather512<<<(N_NODES * 64) / 256, 256, 0, stream>>>(
        (const float4*)B2, rowptr, eidx, (float4*)B1);
    k_gemm_mfma<false, false><<<gemm_grid, 512, 0, stream>>>(
        B1, W2a, b2a, nullptr, nullptr, B2, N_NODES, DIM_H, DIM_H, DIM_H);
    hipMemsetAsync(csum, 0, 4096, stream);
    k_colstats<<<dim3(2, 128), 256, 0, stream>>>(B2, csum, csq);
    k_fold<<<1, 512, 0, stream>>>(csum, csq, g2, be2, sf, cf);
    k_gemm_mfma<true, true><<<gemm_grid, 512, 0, stream>>>(
        B2, W2b, b2b, sf, cf, B1, N_NODES, DIM_H, DIM_H, DIM_H);

    // ---- pool + head ----
    hipMemsetAsync(pooled, 0, (size_t)N_GRAPHS * DIM_H * 4, stream);
    k_pool<<<(N_NODES + 127) / 128, 256, 0, stream>>>(B1, batch, pooled);
    k_head1<<<N_GRAPHS, 512, 0, stream>>>(pooled, Wl1, bl1, qbuf);
    k_head2<<<3, 256, 0, stream>>>(qbuf, Wl2, bl2, (float*)d_out);
}

// Round 9
// 908.738 us; speedup vs baseline: 8.9173x; 1.1575x over previous
//
#include <hip/hip_runtime.h>
#include <cstdint>
#include <cstddef>

// Problem constants (from reference setup_inputs)
#define N_NODES  50000
#define N_EDGES  800000
#define DIM_IN   128
#define DIM_H    512
#define N_GRAPHS 64
#define DIM_OUT  10
#define BN_EPS   1e-5f

typedef _Float16 h16;
using f16x8 = __attribute__((ext_vector_type(8))) _Float16;
using f32x4 = __attribute__((ext_vector_type(4))) float;

__device__ inline float4 add4(float4 a, float4 b) {
    return make_float4(a.x + b.x, a.y + b.y, a.z + b.z, a.w + b.w);
}

// ---------------------------------------------------------------------------
// CSR build: counting sort of edges by dst.
// ---------------------------------------------------------------------------
__global__ __launch_bounds__(256) void k_deg(
    const int* __restrict__ dst, int* __restrict__ deg)
{
    int t = blockIdx.x * 256 + threadIdx.x;
    if (t < N_EDGES) atomicAdd(&deg[dst[t]], 1);
}

// single-block exclusive scan of deg[0..N) -> rowptr[0..N], rowptr[N]=E
__global__ __launch_bounds__(1024) void k_scan(
    const int* __restrict__ deg, int* __restrict__ rowptr)
{
    __shared__ int part[1024];
    const int t = threadIdx.x;
    const int CH = (N_NODES + 1023) / 1024;   // 49
    const int base = t * CH;
    int s = 0;
    for (int i = 0; i < CH; ++i) {
        int idx = base + i;
        if (idx < N_NODES) s += deg[idx];
    }
    part[t] = s;
    __syncthreads();
    for (int off = 1; off < 1024; off <<= 1) {
        int v = (t >= off) ? part[t - off] : 0;
        __syncthreads();
        part[t] += v;
        __syncthreads();
    }
    int run = (t == 0) ? 0 : part[t - 1];
    for (int i = 0; i < CH; ++i) {
        int idx = base + i;
        if (idx < N_NODES) {
            rowptr[idx] = run;
            run += deg[idx];
        } else if (idx == N_NODES) {
            rowptr[idx] = run;                 // == N_EDGES
        }
    }
}

// cursor starts as copy of rowptr[0..N); eidx[pos] = src for each edge
__global__ __launch_bounds__(256) void k_fill(
    const int* __restrict__ src, const int* __restrict__ dst,
    int* __restrict__ cursor, int* __restrict__ eidx)
{
    int t = blockIdx.x * 256 + threadIdx.x;
    if (t >= N_EDGES) return;
    int pos = atomicAdd(&cursor[dst[t]], 1);
    eidx[pos] = src[t];
}

// ---------------------------------------------------------------------------
// Gather aggregation: out[v] = X[v] + sum_{u in N_in(v)} X[u]
// 128-dim: fp32 source (input x), fp16 output. 16 lanes/node, 8 cols each.
// ---------------------------------------------------------------------------
__global__ __launch_bounds__(256) void k_gather128(
    const float4* __restrict__ X, const int* __restrict__ rowptr,
    const int* __restrict__ eidx, f16x8* __restrict__ out)
{
    int t = blockIdx.x * 256 + threadIdx.x;
    int v = t >> 4, lane = t & 15;
    if (v >= N_NODES) return;
    int r0 = rowptr[v], r1 = rowptr[v + 1];
    float4 a0 = X[(size_t)v * 32 + lane * 2];
    float4 a1 = X[(size_t)v * 32 + lane * 2 + 1];
    for (int j = r0; j < r1; ++j) {
        int s = eidx[j];
        a0 = add4(a0, X[(size_t)s * 32 + lane * 2]);
        a1 = add4(a1, X[(size_t)s * 32 + lane * 2 + 1]);
    }
    f16x8 o;
    o[0] = (h16)a0.x; o[1] = (h16)a0.y; o[2] = (h16)a0.z; o[3] = (h16)a0.w;
    o[4] = (h16)a1.x; o[5] = (h16)a1.y; o[6] = (h16)a1.z; o[7] = (h16)a1.w;
    out[(size_t)v * 16 + lane] = o;
}

// 512-dim: fp16 source/dest, fp32 accumulate. 64 lanes/node, one f16x8 each.
__global__ __launch_bounds__(256) void k_gather512h(
    const f16x8* __restrict__ X, const int* __restrict__ rowptr,
    const int* __restrict__ eidx, f16x8* __restrict__ out)
{
    int t = blockIdx.x * 256 + threadIdx.x;
    int v = t >> 6, lane = t & 63;
    if (v >= N_NODES) return;
    int r0 = rowptr[v], r1 = rowptr[v + 1];
    f16x8 sv = X[(size_t)v * 64 + lane];
    float a[8];
#pragma unroll
    for (int i = 0; i < 8; ++i) a[i] = (float)sv[i];
    for (int j = r0; j < r1; ++j) {
        int s = eidx[j];
        f16x8 b = X[(size_t)s * 64 + lane];
#pragma unroll
        for (int i = 0; i < 8; ++i) a[i] += (float)b[i];
    }
    f16x8 o;
#pragma unroll
    for (int i = 0; i < 8; ++i) o[i] = (h16)a[i];
    out[(size_t)v * 64 + lane] = o;
}

// ---------------------------------------------------------------------------
// MFMA GEMM (fp16 A from global, fp32 B weights, fp16 C out, fp32 accum):
//   C[M,N] = op(A) @ B + bias
//   AFFINE: a -> relu(a*s[k]+c[k]) on A load (folded BN+ReLU), fp32 math
//   RELU: epilogue relu
// BM=128, BN=256, BK=32. 512 threads = 8 waves (2x4), wave tile 64x64,
// 4x4 fragments of v_mfma_f32_16x16x32_f16.
// Fragment maps (gfx950, learn_hip m89-verified family):
//   A: lane l holds A[l&15][8*(l>>4)+j], j=0..7
//   B: lane l holds B[8*(l>>4)+j][l&15]
//   D: lane l reg r holds D[4*(l>>4)+r][l&15]
// ---------------------------------------------------------------------------
template<bool AFFINE, bool RELU>
__global__ __launch_bounds__(512) void k_gemm_mfma(
    const h16* __restrict__ A, const float* __restrict__ B,
    const float* __restrict__ bias, const float* __restrict__ sA,
    const float* __restrict__ cA, h16* __restrict__ C,
    int M, int N, int K, int lda)
{
    __shared__ h16 As[4][128][8];   //  8 KB
    __shared__ h16 Bs[4][256][8];   // 16 KB

    const int tid  = threadIdx.x;
    const int lane = tid & 63;
    const int w    = tid >> 6;          // 0..7
    const int wr   = w >> 2;            // 0..1 (row half)
    const int wc   = w & 3;             // 0..3 (col quarter)
    const int l15  = lane & 15;
    const int lk   = lane >> 4;         // k-group 0..3
    const int m0   = blockIdx.x * 128;
    const int n0   = blockIdx.y * 256;

    // A staging: one (row, kb) 8-half chunk per thread
    const int s_row = tid >> 2;         // 0..127
    const int s_kb  = tid & 3;          // 0..3
    int ar = m0 + s_row; if (ar >= M) ar = M - 1;     // clamp; stores predicated
    const h16* aptr = A + (size_t)ar * lda + s_kb * 8;

    f32x4 acc[4][4];
#pragma unroll
    for (int m = 0; m < 4; ++m)
#pragma unroll
        for (int n = 0; n < 4; ++n)
            acc[m][n] = (f32x4){0.f, 0.f, 0.f, 0.f};

    for (int k0 = 0; k0 < K; k0 += 32) {
        // ---- global loads (regs) ----
        f16x8 av = *reinterpret_cast<const f16x8*>(aptr + k0);
        if (AFFINE) {
            int kk = k0 + s_kb * 8;
            float4 s0 = *reinterpret_cast<const float4*>(&sA[kk]);
            float4 s1 = *reinterpret_cast<const float4*>(&sA[kk + 4]);
            float4 c0 = *reinterpret_cast<const float4*>(&cA[kk]);
            float4 c1 = *reinterpret_cast<const float4*>(&cA[kk + 4]);
            float va[8];
#pragma unroll
            for (int i = 0; i < 8; ++i) va[i] = (float)av[i];
            va[0] = fmaxf(fmaf(va[0], s0.x, c0.x), 0.f);
            va[1] = fmaxf(fmaf(va[1], s0.y, c0.y), 0.f);
            va[2] = fmaxf(fmaf(va[2], s0.z, c0.z), 0.f);
            va[3] = fmaxf(fmaf(va[3], s0.w, c0.w), 0.f);
            va[4] = fmaxf(fmaf(va[4], s1.x, c1.x), 0.f);
            va[5] = fmaxf(fmaf(va[5], s1.y, c1.y), 0.f);
            va[6] = fmaxf(fmaf(va[6], s1.z, c1.z), 0.f);
            va[7] = fmaxf(fmaf(va[7], s1.w, c1.w), 0.f);
#pragma unroll
            for (int i = 0; i < 8; ++i) av[i] = (h16)va[i];
        }

        float bv[2][8];
#pragma unroll
        for (int h = 0; h < 2; ++h) {
            int idx = tid + h * 512;
            int kb = idx >> 8, nc = idx & 255;
            const float* bp = B + (size_t)(k0 + kb * 8) * N + n0 + nc;
#pragma unroll
            for (int j = 0; j < 8; ++j)
                bv[h][j] = bp[(size_t)j * N];
        }

        __syncthreads();   // previous tile fully consumed
        *reinterpret_cast<f16x8*>(&As[s_kb][s_row][0]) = av;
#pragma unroll
        for (int h = 0; h < 2; ++h) {
            int idx = tid + h * 512;
            int kb = idx >> 8, nc = idx & 255;
            f16x8 bw;
#pragma unroll
            for (int j = 0; j < 8; ++j) bw[j] = (h16)bv[h][j];
            *reinterpret_cast<f16x8*>(&Bs[kb][nc][0]) = bw;
        }
        __syncthreads();   // tile ready

        // ---- MFMA: 16 per wave ----
        f16x8 af[4], bf[4];
#pragma unroll
        for (int m = 0; m < 4; ++m)
            af[m] = *reinterpret_cast<const f16x8*>(&As[lk][wr * 64 + m * 16 + l15][0]);
#pragma unroll
        for (int n = 0; n < 4; ++n)
            bf[n] = *reinterpret_cast<const f16x8*>(&Bs[lk][wc * 64 + n * 16 + l15][0]);
#pragma unroll
        for (int m = 0; m < 4; ++m)
#pragma unroll
            for (int n = 0; n < 4; ++n)
                acc[m][n] = __builtin_amdgcn_mfma_f32_16x16x32_f16(
                    af[m], bf[n], acc[m][n], 0, 0, 0);
    }

    // ---- epilogue (fp16 store) ----
#pragma unroll
    for (int n = 0; n < 4; ++n) {
        int col = n0 + wc * 64 + n * 16 + l15;
        float bb = bias[col];
#pragma unroll
        for (int m = 0; m < 4; ++m) {
            int row0 = m0 + wr * 64 + m * 16 + lk * 4;
#pragma unroll
            for (int r = 0; r < 4; ++r) {
                int row = row0 + r;
                if (row < M) {
                    float v = acc[m][n][r] + bb;
                    if (RELU) v = fmaxf(v, 0.f);
                    C[(size_t)row * N + col] = (h16)v;
                }
            }
        }
    }
}

// ---------------------------------------------------------------------------
// Column statistics over T[N_NODES, 512] (fp16): per-column sum / sum-of-sq
// ---------------------------------------------------------------------------
__global__ __launch_bounds__(256) void k_colstats(
    const h16* __restrict__ T, float* __restrict__ csum, float* __restrict__ csq)
{
    int c = blockIdx.x * 256 + threadIdx.x;
    int nchunk = gridDim.y, chunk = blockIdx.y;
    int r0 = (int)(((long long)N_NODES * chunk) / nchunk);
    int r1 = (int)(((long long)N_NODES * (chunk + 1)) / nchunk);
    float s = 0.f, ss = 0.f;
    for (int r = r0; r < r1; ++r) {
        float v = (float)T[(size_t)r * DIM_H + c];
        s += v;
        ss += v * v;
    }
    atomicAdd(&csum[c], s);
    atomicAdd(&csq[c], ss);
}

// Fold BN into per-column affine: s = g*rsqrt(var+eps), c = beta - mu*s
__global__ void k_fold(const float* __restrict__ csum, const float* __restrict__ csq,
                       const float* __restrict__ g, const float* __restrict__ be,
                       float* __restrict__ sf, float* __restrict__ cf)
{
    int c = threadIdx.x;   // 512
    const float invM = 1.0f / (float)N_NODES;
    float mu  = csum[c] * invM;
    float var = csq[c] * invM - mu * mu;
    float s   = g[c] * rsqrtf(var + BN_EPS);
    sf[c] = s;
    cf[c] = be[c] - mu * s;
}

// ---------------------------------------------------------------------------
// Graph pooling (fp16 H): batch sorted -> local accumulate, boundary atomics
// ---------------------------------------------------------------------------
__global__ __launch_bounds__(256) void k_pool(
    const h16* __restrict__ H, const int* __restrict__ batch,
    float* __restrict__ pooled)
{
    __shared__ int bg[128];
    int base = blockIdx.x * 128;
    if (threadIdx.x < 128) {
        int r = base + threadIdx.x;
        bg[threadIdx.x] = (r < N_NODES) ? batch[r] : -1;
    }
    __syncthreads();
    int c0 = threadIdx.x;
    float a0 = 0.f, a1 = 0.f;
    int cur = bg[0];
    for (int r = 0; r < 128; ++r) {
        int g = bg[r];
        if (g < 0) break;
        if (g != cur) {
            atomicAdd(&pooled[cur * DIM_H + c0],       a0);
            atomicAdd(&pooled[cur * DIM_H + c0 + 256], a1);
            a0 = a1 = 0.f;
            cur = g;
        }
        size_t row = (size_t)(base + r);
        a0 += (float)H[row * DIM_H + c0];
        a1 += (float)H[row * DIM_H + c0 + 256];
    }
    if (cur >= 0) {
        atomicAdd(&pooled[cur * DIM_H + c0],       a0);
        atomicAdd(&pooled[cur * DIM_H + c0 + 256], a1);
    }
}

// head1: q[g] = relu(pooled[g] @ Wl1 + bl1)
__global__ __launch_bounds__(512) void k_head1(
    const float* __restrict__ pooled, const float* __restrict__ W,
    const float* __restrict__ b, float* __restrict__ q)
{
    __shared__ float row[DIM_H];
    int g = blockIdx.x, c = threadIdx.x;
    row[c] = pooled[(size_t)g * DIM_H + c];
    __syncthreads();
    float acc = 0.f;
    for (int k = 0; k < DIM_H; ++k)
        acc = fmaf(row[k], W[(size_t)k * DIM_H + c], acc);
    q[(size_t)g * DIM_H + c] = fmaxf(acc + b[c], 0.f);
}

// head2: out[g] = q[g] @ Wl2 + bl2
__global__ __launch_bounds__(256) void k_head2(
    const float* __restrict__ q, const float* __restrict__ W,
    const float* __restrict__ b, float* __restrict__ out)
{
    int t = blockIdx.x * 256 + threadIdx.x;
    if (t >= N_GRAPHS * DIM_OUT) return;
    int g = t / DIM_OUT, c = t % DIM_OUT;
    float acc = 0.f;
    for (int k = 0; k < DIM_H; ++k)
        acc = fmaf(q[(size_t)g * DIM_H + k], W[(size_t)k * DIM_OUT + c], acc);
    out[t] = acc + b[c];
}

// ---------------------------------------------------------------------------
extern "C" void kernel_launch(void* const* d_in, const int* in_sizes, int n_in,
                              void* d_out, int out_size, void* d_ws, size_t ws_size,
                              hipStream_t stream)
{
    const float* x   = (const float*)d_in[0];
    const int*   ei  = (const int*)d_in[1];
    const int*   src = ei;
    const int*   dst = ei + N_EDGES;
    const int*   batch = (const int*)d_in[2];
    const float* W1a = (const float*)d_in[3];
    const float* b1a = (const float*)d_in[4];
    const float* g1  = (const float*)d_in[5];
    const float* be1 = (const float*)d_in[6];
    const float* W1b = (const float*)d_in[7];
    const float* b1b = (const float*)d_in[8];
    const float* W2a = (const float*)d_in[9];
    const float* b2a = (const float*)d_in[10];
    const float* g2  = (const float*)d_in[11];
    const float* be2 = (const float*)d_in[12];
    const float* W2b = (const float*)d_in[13];
    const float* b2b = (const float*)d_in[14];
    const float* Wl1 = (const float*)d_in[15];
    const float* bl1 = (const float*)d_in[16];
    const float* Wl2 = (const float*)d_in[17];
    const float* bl2 = (const float*)d_in[18];

    char* ws = (char*)d_ws;
    const size_t ROW_H = (size_t)N_NODES * DIM_H * 2;   // 51,200,000

    if (ws_size < 110000000ull) {
        hipMemsetAsync(d_out, 0, (size_t)out_size * 4, stream);
        return;
    }
    h16* B1h = (h16*)(ws + 0);
    h16* B2h = (h16*)(ws + ROW_H);
    h16* XAh = B2h;                                   // 12.8 MB, dead after GEMM1
    char* cp  = ws + 2 * ROW_H;                       // 102,400,000
    int* deg    = (int*)(cp + 0);
    int* rowptr = (int*)(cp + 200192);
    int* cursor = (int*)(cp + 400384);
    int* eidx   = (int*)(cp + 600576);
    char* sm    = cp + 3800576;
    float* csum   = (float*)(sm + 0);
    float* csq    = (float*)(sm + 2048);
    float* sf     = (float*)(sm + 4096);
    float* cf     = (float*)(sm + 6144);
    float* pooled = (float*)(sm + 8192);
    float* qbuf   = (float*)(sm + 8192 + 131072);

    const dim3 gemm_grid(391, 2);   // ceil(50000/128) x 512/256
    const int EB = (N_EDGES + 255) / 256;

    // ---- CSR build (counting sort by dst) ----
    hipMemsetAsync(deg, 0, (size_t)N_NODES * 4, stream);
    k_deg<<<EB, 256, 0, stream>>>(dst, deg);
    k_scan<<<1, 1024, 0, stream>>>(deg, rowptr);
    hipMemcpyAsync(cursor, rowptr, (size_t)N_NODES * 4, hipMemcpyDeviceToDevice, stream);
    k_fill<<<EB, 256, 0, stream>>>(src, dst, cursor, eidx);

    // ---- layer 1 ----
    k_gather128<<<(N_NODES * 16 + 255) / 256, 256, 0, stream>>>(
        (const float4*)x, rowptr, eidx, (f16x8*)XAh);
    k_gemm_mfma<false, false><<<gemm_grid, 512, 0, stream>>>(
        XAh, W1a, b1a, nullptr, nullptr, B1h, N_NODES, DIM_H, DIM_IN, DIM_IN);
    hipMemsetAsync(csum, 0, 4096, stream);
    k_colstats<<<dim3(2, 128), 256, 0, stream>>>(B1h, csum, csq);
    k_fold<<<1, 512, 0, stream>>>(csum, csq, g1, be1, sf, cf);
    k_gemm_mfma<true, true><<<gemm_grid, 512, 0, stream>>>(
        B1h, W1b, b1b, sf, cf, B2h, N_NODES, DIM_H, DIM_H, DIM_H);

    // ---- layer 2 ----
    k_gather512h<<<(N_NODES * 64) / 256, 256, 0, stream>>>(
        (const f16x8*)B2h, rowptr, eidx, (f16x8*)B1h);
    k_gemm_mfma<false, false><<<gemm_grid, 512, 0, stream>>>(
        B1h, W2a, b2a, nullptr, nullptr, B2h, N_NODES, DIM_H, DIM_H, DIM_H);
    hipMemsetAsync(csum, 0, 4096, stream);
    k_colstats<<<dim3(2, 128), 256, 0, stream>>>(B2h, csum, csq);
    k_fold<<<1, 512, 0, stream>>>(csum, csq, g2, be2, sf, cf);
    k_gemm_mfma<true, true><<<gemm_grid, 512, 0, stream>>>(
        B2h, W2b, b2b, sf, cf, B1h, N_NODES, DIM_H, DIM_H, DIM_H);

    // ---- pool + head ----
    hipMemsetAsync(pooled, 0, (size_t)N_GRAPHS * DIM_H * 4, stream);
    k_pool<<<(N_NODES + 127) / 128, 256, 0, stream>>>(B1h, batch, pooled);
    k_head1<<<N_GRAPHS, 512, 0, stream>>>(pooled, Wl1, bl1, qbuf);
    k_head2<<<3, 256, 0, stream>>>(qbuf, Wl2, bl2, (float*)d_out);
}

// Round 11
// 809.249 us; speedup vs baseline: 10.0136x; 1.1229x over previous
//
#include <hip/hip_runtime.h>
#include <cstdint>
#include <cstddef>

// Problem constants (from reference setup_inputs)
#define N_NODES  50000
#define N_EDGES  800000
#define DIM_IN   128
#define DIM_H    512
#define N_GRAPHS 64
#define DIM_OUT  10
#define BN_EPS   1e-5f

typedef _Float16 h16;
using f16x8 = __attribute__((ext_vector_type(8))) _Float16;
using f32x4 = __attribute__((ext_vector_type(4))) float;

__device__ inline float4 add4(float4 a, float4 b) {
    return make_float4(a.x + b.x, a.y + b.y, a.z + b.z, a.w + b.w);
}

// ---------------------------------------------------------------------------
// Weight cast+transpose: Wt[n][k] = (h16)W[k][n].  Run once per weight.
// ---------------------------------------------------------------------------
__global__ __launch_bounds__(256) void k_wcast(
    const float* __restrict__ W, h16* __restrict__ Wt, int K, int N)
{
    int t = blockIdx.x * 256 + threadIdx.x;
    int total = (K >> 3) * N;
    if (t >= total) return;
    int k8 = t / N;
    int n  = t - k8 * N;
    f16x8 o;
#pragma unroll
    for (int j = 0; j < 8; ++j)
        o[j] = (h16)W[(size_t)(k8 * 8 + j) * N + n];
    *reinterpret_cast<f16x8*>(&Wt[(size_t)n * K + k8 * 8]) = o;
}

// ---------------------------------------------------------------------------
// CSR build: counting sort of edges by dst.
// ---------------------------------------------------------------------------
__global__ __launch_bounds__(256) void k_deg(
    const int* __restrict__ dst, int* __restrict__ deg)
{
    int t = blockIdx.x * 256 + threadIdx.x;
    if (t < N_EDGES) atomicAdd(&deg[dst[t]], 1);
}

// single-block exclusive scan; writes rowptr[0..N] and cursor[0..N)
__global__ __launch_bounds__(1024) void k_scan(
    const int* __restrict__ deg, int* __restrict__ rowptr, int* __restrict__ cursor)
{
    __shared__ int part[1024];
    const int t = threadIdx.x;
    const int CH = (N_NODES + 1023) / 1024;   // 49
    const int base = t * CH;
    int s = 0;
    for (int i = 0; i < CH; ++i) {
        int idx = base + i;
        if (idx < N_NODES) s += deg[idx];
    }
    part[t] = s;
    __syncthreads();
    for (int off = 1; off < 1024; off <<= 1) {
        int v = (t >= off) ? part[t - off] : 0;
        __syncthreads();
        part[t] += v;
        __syncthreads();
    }
    int run = (t == 0) ? 0 : part[t - 1];
    for (int i = 0; i < CH; ++i) {
        int idx = base + i;
        if (idx < N_NODES) {
            rowptr[idx] = run;
            cursor[idx] = run;
            run += deg[idx];
        } else if (idx == N_NODES) {
            rowptr[idx] = run;                 // == N_EDGES
        }
    }
}

__global__ __launch_bounds__(256) void k_fill(
    const int* __restrict__ src, const int* __restrict__ dst,
    int* __restrict__ cursor, int* __restrict__ eidx)
{
    int t = blockIdx.x * 256 + threadIdx.x;
    if (t >= N_EDGES) return;
    int pos = atomicAdd(&cursor[dst[t]], 1);
    eidx[pos] = src[t];
}

// ---------------------------------------------------------------------------
// Gather aggregation: out[v] = X[v] + sum_{u in N_in(v)} X[u]
// 128-dim: fp32 source (input x), fp16 output. 16 lanes/node, 8 cols each.
// ---------------------------------------------------------------------------
__global__ __launch_bounds__(256) void k_gather128(
    const float4* __restrict__ X, const int* __restrict__ rowptr,
    const int* __restrict__ eidx, f16x8* __restrict__ out)
{
    int t = blockIdx.x * 256 + threadIdx.x;
    int v = t >> 4, lane = t & 15;
    if (v >= N_NODES) return;
    int r0 = rowptr[v], r1 = rowptr[v + 1];
    float4 a0 = X[(size_t)v * 32 + lane * 2];
    float4 a1 = X[(size_t)v * 32 + lane * 2 + 1];
    for (int j = r0; j < r1; ++j) {
        int s = eidx[j];
        a0 = add4(a0, X[(size_t)s * 32 + lane * 2]);
        a1 = add4(a1, X[(size_t)s * 32 + lane * 2 + 1]);
    }
    f16x8 o;
    o[0] = (h16)a0.x; o[1] = (h16)a0.y; o[2] = (h16)a0.z; o[3] = (h16)a0.w;
    o[4] = (h16)a1.x; o[5] = (h16)a1.y; o[6] = (h16)a1.z; o[7] = (h16)a1.w;
    out[(size_t)v * 16 + lane] = o;
}

// 512-dim: fp16 src/dst, fp32 accumulate, 4-deep unrolled neighbor loop.
__global__ __launch_bounds__(256) void k_gather512h(
    const f16x8* __restrict__ X, const int* __restrict__ rowptr,
    const int* __restrict__ eidx, f16x8* __restrict__ out)
{
    int t = blockIdx.x * 256 + threadIdx.x;
    int v = t >> 6, lane = t & 63;
    if (v >= N_NODES) return;
    int r0 = rowptr[v], r1 = rowptr[v + 1];
    f16x8 sv = X[(size_t)v * 64 + lane];
    float a[8];
#pragma unroll
    for (int i = 0; i < 8; ++i) a[i] = (float)sv[i];
    int j = r0;
    for (; j + 3 < r1; j += 4) {
        int s0 = eidx[j], s1 = eidx[j + 1], s2 = eidx[j + 2], s3 = eidx[j + 3];
        f16x8 b0 = X[(size_t)s0 * 64 + lane];
        f16x8 b1 = X[(size_t)s1 * 64 + lane];
        f16x8 b2 = X[(size_t)s2 * 64 + lane];
        f16x8 b3 = X[(size_t)s3 * 64 + lane];
#pragma unroll
        for (int i = 0; i < 8; ++i)
            a[i] += ((float)b0[i] + (float)b1[i]) + ((float)b2[i] + (float)b3[i]);
    }
    for (; j < r1; ++j) {
        f16x8 b = X[(size_t)eidx[j] * 64 + lane];
#pragma unroll
        for (int i = 0; i < 8; ++i) a[i] += (float)b[i];
    }
    f16x8 o;
#pragma unroll
    for (int i = 0; i < 8; ++i) o[i] = (h16)a[i];
    out[(size_t)v * 64 + lane] = o;
}

// ---------------------------------------------------------------------------
// MFMA GEMM (fp16 A + fp16 k-major B, fp32 accum, fp16 C):
//   C[M,N] = op(A) @ B + bias
//   AFFINE: a -> relu(a*s[k]+c[k]) on A load (folded BN+ReLU)
//   RELU: epilogue relu
//   STATS: fused per-column sum / sum-of-squares of C (pre-ReLU, post-bias)
// BM=128, BN=256, BK=32. 512 threads = 8 waves (2x4), wave tile 64x64,
// 4x4 fragments of v_mfma_f32_16x16x32_f16.
// Fragment maps (gfx950, learn_hip m89-verified family):
//   A: lane l holds A[l&15][8*(l>>4)+j] ; B: lane l holds B[8*(l>>4)+j][l&15]
//   D: lane l reg r holds D[4*(l>>4)+r][l&15]
// ---------------------------------------------------------------------------
template<bool AFFINE, bool RELU, bool STATS>
__global__ __launch_bounds__(512) void k_gemm_mfma(
    const h16* __restrict__ A, const h16* __restrict__ Bt,
    const float* __restrict__ bias, const float* __restrict__ sA,
    const float* __restrict__ cA, h16* __restrict__ C,
    float* __restrict__ csum, float* __restrict__ csq,
    int M, int N, int K, int lda)
{
    __shared__ h16 As[4][128][8];   //  8 KB
    __shared__ h16 Bs[4][256][8];   // 16 KB

    const int tid  = threadIdx.x;
    const int lane = tid & 63;
    const int w    = tid >> 6;          // 0..7
    const int wr   = w >> 2;            // 0..1 (row half)
    const int wc   = w & 3;             // 0..3 (col quarter)
    const int l15  = lane & 15;
    const int lk   = lane >> 4;         // k-group 0..3
    const int m0   = blockIdx.x * 128;
    const int n0   = blockIdx.y * 256;

    // A staging: one (row, kb) 8-half chunk per thread
    const int s_row = tid >> 2;         // 0..127
    const int s_kb  = tid & 3;          // 0..3
    int ar = m0 + s_row; if (ar >= M) ar = M - 1;     // clamp; stores predicated
    const h16* aptr = A + (size_t)ar * lda + s_kb * 8;
    // B staging: two (kb, nc) chunks per thread from k-major Wt
    const int b_kb0 = tid >> 8, b_nc0 = tid & 255;          // idx = tid
    const int b_kb1 = (tid + 512) >> 8, b_nc1 = tid & 255;  // idx = tid+512

    f32x4 acc[4][4];
#pragma unroll
    for (int m = 0; m < 4; ++m)
#pragma unroll
        for (int n = 0; n < 4; ++n)
            acc[m][n] = (f32x4){0.f, 0.f, 0.f, 0.f};

    for (int k0 = 0; k0 < K; k0 += 32) {
        // ---- global loads (regs) ----
        f16x8 av = *reinterpret_cast<const f16x8*>(aptr + k0);
        if (AFFINE) {
            int kk = k0 + s_kb * 8;
            float4 s0 = *reinterpret_cast<const float4*>(&sA[kk]);
            float4 s1 = *reinterpret_cast<const float4*>(&sA[kk + 4]);
            float4 c0 = *reinterpret_cast<const float4*>(&cA[kk]);
            float4 c1 = *reinterpret_cast<const float4*>(&cA[kk + 4]);
            float va[8];
#pragma unroll
            for (int i = 0; i < 8; ++i) va[i] = (float)av[i];
            va[0] = fmaxf(fmaf(va[0], s0.x, c0.x), 0.f);
            va[1] = fmaxf(fmaf(va[1], s0.y, c0.y), 0.f);
            va[2] = fmaxf(fmaf(va[2], s0.z, c0.z), 0.f);
            va[3] = fmaxf(fmaf(va[3], s0.w, c0.w), 0.f);
            va[4] = fmaxf(fmaf(va[4], s1.x, c1.x), 0.f);
            va[5] = fmaxf(fmaf(va[5], s1.y, c1.y), 0.f);
            va[6] = fmaxf(fmaf(va[6], s1.z, c1.z), 0.f);
            va[7] = fmaxf(fmaf(va[7], s1.w, c1.w), 0.f);
#pragma unroll
            for (int i = 0; i < 8; ++i) av[i] = (h16)va[i];
        }
        f16x8 bw0 = *reinterpret_cast<const f16x8*>(
            &Bt[(size_t)(n0 + b_nc0) * K + k0 + b_kb0 * 8]);
        f16x8 bw1 = *reinterpret_cast<const f16x8*>(
            &Bt[(size_t)(n0 + b_nc1) * K + k0 + b_kb1 * 8]);

        __syncthreads();   // previous tile fully consumed
        *reinterpret_cast<f16x8*>(&As[s_kb][s_row][0]) = av;
        *reinterpret_cast<f16x8*>(&Bs[b_kb0][b_nc0][0]) = bw0;
        *reinterpret_cast<f16x8*>(&Bs[b_kb1][b_nc1][0]) = bw1;
        __syncthreads();   // tile ready

        // ---- MFMA: 16 per wave ----
        f16x8 af[4], bf[4];
#pragma unroll
        for (int m = 0; m < 4; ++m)
            af[m] = *reinterpret_cast<const f16x8*>(&As[lk][wr * 64 + m * 16 + l15][0]);
#pragma unroll
        for (int n = 0; n < 4; ++n)
            bf[n] = *reinterpret_cast<const f16x8*>(&Bs[lk][wc * 64 + n * 16 + l15][0]);
#pragma unroll
        for (int m = 0; m < 4; ++m)
#pragma unroll
            for (int n = 0; n < 4; ++n)
                acc[m][n] = __builtin_amdgcn_mfma_f32_16x16x32_f16(
                    af[m], bf[n], acc[m][n], 0, 0, 0);
    }

    // ---- epilogue (fp16 store + optional fused column stats) ----
#pragma unroll
    for (int n = 0; n < 4; ++n) {
        int col = n0 + wc * 64 + n * 16 + l15;
        float bb = bias[col];
        float sp = 0.f, qp = 0.f;
#pragma unroll
        for (int m = 0; m < 4; ++m) {
            int row0 = m0 + wr * 64 + m * 16 + lk * 4;
#pragma unroll
            for (int r = 0; r < 4; ++r) {
                int row = row0 + r;
                if (row < M) {
                    float v = acc[m][n][r] + bb;
                    if (STATS) { sp += v; qp += v * v; }
                    if (RELU) v = fmaxf(v, 0.f);
                    C[(size_t)row * N + col] = (h16)v;
                }
            }
        }
        if (STATS) {
            sp += __shfl_xor(sp, 16); qp += __shfl_xor(qp, 16);
            sp += __shfl_xor(sp, 32); qp += __shfl_xor(qp, 32);
            if (lk == 0) {
                atomicAdd(&csum[col], sp);
                atomicAdd(&csq[col], qp);
            }
        }
    }
}

// Fold BN into per-column affine: s = g*rsqrt(var+eps), c = beta - mu*s
__global__ void k_fold(const float* __restrict__ csum, const float* __restrict__ csq,
                       const float* __restrict__ g, const float* __restrict__ be,
                       float* __restrict__ sf, float* __restrict__ cf)
{
    int c = threadIdx.x;   // 512
    const float invM = 1.0f / (float)N_NODES;
    float mu  = csum[c] * invM;
    float var = csq[c] * invM - mu * mu;
    float s   = g[c] * rsqrtf(var + BN_EPS);
    sf[c] = s;
    cf[c] = be[c] - mu * s;
}

// ---------------------------------------------------------------------------
// Graph pooling (fp16 H): batch sorted -> local accumulate, boundary atomics
// ---------------------------------------------------------------------------
__global__ __launch_bounds__(256) void k_pool(
    const h16* __restrict__ H, const int* __restrict__ batch,
    float* __restrict__ pooled)
{
    __shared__ int bg[128];
    int base = blockIdx.x * 128;
    if (threadIdx.x < 128) {
        int r = base + threadIdx.x;
        bg[threadIdx.x] = (r < N_NODES) ? batch[r] : -1;
    }
    __syncthreads();
    int c0 = threadIdx.x;
    float a0 = 0.f, a1 = 0.f;
    int cur = bg[0];
    for (int r = 0; r < 128; ++r) {
        int g = bg[r];
        if (g < 0) break;
        if (g != cur) {
            atomicAdd(&pooled[cur * DIM_H + c0],       a0);
            atomicAdd(&pooled[cur * DIM_H + c0 + 256], a1);
            a0 = a1 = 0.f;
            cur = g;
        }
        size_t row = (size_t)(base + r);
        a0 += (float)H[row * DIM_H + c0];
        a1 += (float)H[row * DIM_H + c0 + 256];
    }
    if (cur >= 0) {
        atomicAdd(&pooled[cur * DIM_H + c0],       a0);
        atomicAdd(&pooled[cur * DIM_H + c0 + 256], a1);
    }
}

// head1: q[g] = relu(pooled[g] @ Wl1 + bl1)
__global__ __launch_bounds__(512) void k_head1(
    const float* __restrict__ pooled, const float* __restrict__ W,
    const float* __restrict__ b, float* __restrict__ q)
{
    __shared__ float row[DIM_H];
    int g = blockIdx.x, c = threadIdx.x;
    row[c] = pooled[(size_t)g * DIM_H + c];
    __syncthreads();
    float acc = 0.f;
    for (int k = 0; k < DIM_H; ++k)
        acc = fmaf(row[k], W[(size_t)k * DIM_H + c], acc);
    q[(size_t)g * DIM_H + c] = fmaxf(acc + b[c], 0.f);
}

// head2: out[g] = q[g] @ Wl2 + bl2
__global__ __launch_bounds__(256) void k_head2(
    const float* __restrict__ q, const float* __restrict__ W,
    const float* __restrict__ b, float* __restrict__ out)
{
    int t = blockIdx.x * 256 + threadIdx.x;
    if (t >= N_GRAPHS * DIM_OUT) return;
    int g = t / DIM_OUT, c = t % DIM_OUT;
    float acc = 0.f;
    for (int k = 0; k < DIM_H; ++k)
        acc = fmaf(q[(size_t)g * DIM_H + k], W[(size_t)k * DIM_OUT + c], acc);
    out[t] = acc + b[c];
}

// ---------------------------------------------------------------------------
extern "C" void kernel_launch(void* const* d_in, const int* in_sizes, int n_in,
                              void* d_out, int out_size, void* d_ws, size_t ws_size,
                              hipStream_t stream)
{
    const float* x   = (const float*)d_in[0];
    const int*   ei  = (const int*)d_in[1];
    const int*   src = ei;
    const int*   dst = ei + N_EDGES;
    const int*   batch = (const int*)d_in[2];
    const float* W1a = (const float*)d_in[3];
    const float* b1a = (const float*)d_in[4];
    const float* g1  = (const float*)d_in[5];
    const float* be1 = (const float*)d_in[6];
    const float* W1b = (const float*)d_in[7];
    const float* b1b = (const float*)d_in[8];
    const float* W2a = (const float*)d_in[9];
    const float* b2a = (const float*)d_in[10];
    const float* g2  = (const float*)d_in[11];
    const float* be2 = (const float*)d_in[12];
    const float* W2b = (const float*)d_in[13];
    const float* b2b = (const float*)d_in[14];
    const float* Wl1 = (const float*)d_in[15];
    const float* bl1 = (const float*)d_in[16];
    const float* Wl2 = (const float*)d_in[17];
    const float* bl2 = (const float*)d_in[18];

    char* ws = (char*)d_ws;
    const size_t ROW_H = (size_t)N_NODES * DIM_H * 2;   // 51,200,000

    if (ws_size < 110000000ull) {
        hipMemsetAsync(d_out, 0, (size_t)out_size * 4, stream);
        return;
    }
    h16* B1h = (h16*)(ws + 0);
    h16* B2h = (h16*)(ws + ROW_H);
    h16* XAh = B2h;                                   // 12.8 MB, dead after GEMM1
    char* cp  = ws + 2 * ROW_H;                       // 102,400,000
    int* deg    = (int*)(cp + 0);
    int* rowptr = (int*)(cp + 200192);
    int* cursor = (int*)(cp + 400384);
    int* eidx   = (int*)(cp + 600576);
    char* sm    = cp + 3800576;
    float* csum   = (float*)(sm + 0);
    float* csq    = (float*)(sm + 2048);
    float* sf     = (float*)(sm + 4096);
    float* cf     = (float*)(sm + 6144);
    float* pooled = (float*)(sm + 8192);
    float* qbuf   = (float*)(sm + 8192 + 131072);
    char* wt = sm + 8192 + 2 * 131072;
    h16* Wt1a = (h16*)(wt);                           // [512][128] 128 KB
    h16* Wt1b = (h16*)(wt + 131072);                  // [512][512] 512 KB
    h16* Wt2a = (h16*)(wt + 131072 + 524288);
    h16* Wt2b = (h16*)(wt + 131072 + 2 * 524288);

    const dim3 gemm_grid(391, 2);   // ceil(50000/128) x 512/256
    const int EB = (N_EDGES + 255) / 256;

    // ---- weight cast+transpose (once) ----
    k_wcast<<<32, 256, 0, stream>>>(W1a, Wt1a, DIM_IN, DIM_H);
    k_wcast<<<128, 256, 0, stream>>>(W1b, Wt1b, DIM_H, DIM_H);
    k_wcast<<<128, 256, 0, stream>>>(W2a, Wt2a, DIM_H, DIM_H);
    k_wcast<<<128, 256, 0, stream>>>(W2b, Wt2b, DIM_H, DIM_H);

    // ---- CSR build (counting sort by dst) ----
    hipMemsetAsync(deg, 0, (size_t)N_NODES * 4, stream);
    k_deg<<<EB, 256, 0, stream>>>(dst, deg);
    k_scan<<<1, 1024, 0, stream>>>(deg, rowptr, cursor);
    k_fill<<<EB, 256, 0, stream>>>(src, dst, cursor, eidx);

    // ---- layer 1 ----
    k_gather128<<<(N_NODES * 16 + 255) / 256, 256, 0, stream>>>(
        (const float4*)x, rowptr, eidx, (f16x8*)XAh);
    hipMemsetAsync(csum, 0, 4096, stream);
    k_gemm_mfma<false, false, true><<<gemm_grid, 512, 0, stream>>>(
        XAh, Wt1a, b1a, nullptr, nullptr, B1h, csum, csq,
        N_NODES, DIM_H, DIM_IN, DIM_IN);
    k_fold<<<1, 512, 0, stream>>>(csum, csq, g1, be1, sf, cf);
    k_gemm_mfma<true, true, false><<<gemm_grid, 512, 0, stream>>>(
        B1h, Wt1b, b1b, sf, cf, B2h, nullptr, nullptr,
        N_NODES, DIM_H, DIM_H, DIM_H);

    // ---- layer 2 ----
    k_gather512h<<<(N_NODES * 64) / 256, 256, 0, stream>>>(
        (const f16x8*)B2h, rowptr, eidx, (f16x8*)B1h);
    hipMemsetAsync(csum, 0, 4096, stream);
    k_gemm_mfma<false, false, true><<<gemm_grid, 512, 0, stream>>>(
        B1h, Wt2a, b2a, nullptr, nullptr, B2h, csum, csq,
        N_NODES, DIM_H, DIM_H, DIM_H);
    k_fold<<<1, 512, 0, stream>>>(csum, csq, g2, be2, sf, cf);
    k_gemm_mfma<true, true, false><<<gemm_grid, 512, 0, stream>>>(
        B2h, Wt2b, b2b, sf, cf, B1h, nullptr, nullptr,
        N_NODES, DIM_H, DIM_H, DIM_H);

    // ---- pool + head ----
    hipMemsetAsync(pooled, 0, (size_t)N_GRAPHS * DIM_H * 4, stream);
    k_pool<<<(N_NODES + 127) / 128, 256, 0, stream>>>(B1h, batch, pooled);
    k_head1<<<N_GRAPHS, 512, 0, stream>>>(pooled, Wl1, bl1, qbuf);
    k_head2<<<3, 256, 0, stream>>>(qbuf, Wl2, bl2, (float*)d_out);
}

// Round 12
// 691.246 us; speedup vs baseline: 11.7230x; 1.1707x over previous
//
#include <hip/hip_runtime.h>
#include <cstdint>
#include <cstddef>

// Problem constants (from reference setup_inputs)
#define N_NODES  50000
#define N_EDGES  800000
#define DIM_IN   128
#define DIM_H    512
#define N_GRAPHS 64
#define DIM_OUT  10
#define BN_EPS   1e-5f
#define SCAN_B   196   // ceil(N_NODES / 256)

typedef _Float16 h16;
using f16x8 = __attribute__((ext_vector_type(8))) _Float16;
using f32x4 = __attribute__((ext_vector_type(4))) float;

__device__ inline float4 add4(float4 a, float4 b) {
    return make_float4(a.x + b.x, a.y + b.y, a.z + b.z, a.w + b.w);
}

// ---------------------------------------------------------------------------
// Weight cast+transpose: Wt[n][k] = (h16)W[k][n].  Run once per weight.
// ---------------------------------------------------------------------------
__global__ __launch_bounds__(256) void k_wcast(
    const float* __restrict__ W, h16* __restrict__ Wt, int K, int N)
{
    int t = blockIdx.x * 256 + threadIdx.x;
    int total = (K >> 3) * N;
    if (t >= total) return;
    int k8 = t / N;
    int n  = t - k8 * N;
    f16x8 o;
#pragma unroll
    for (int j = 0; j < 8; ++j)
        o[j] = (h16)W[(size_t)(k8 * 8 + j) * N + n];
    *reinterpret_cast<f16x8*>(&Wt[(size_t)n * K + k8 * 8]) = o;
}

// ---------------------------------------------------------------------------
// CSR build: counting sort of edges by dst.  Hierarchical 3-phase scan.
// ---------------------------------------------------------------------------
__global__ __launch_bounds__(256) void k_deg(
    const int* __restrict__ dst, int* __restrict__ deg)
{
    int t = blockIdx.x * 256 + threadIdx.x;
    if (t < N_EDGES) atomicAdd(&deg[dst[t]], 1);
}

// phase 1: per-block (256-chunk) sums of deg
__global__ __launch_bounds__(256) void k_scan1(
    const int* __restrict__ deg, int* __restrict__ bsum)
{
    __shared__ int s[256];
    int tid = threadIdx.x;
    int i = blockIdx.x * 256 + tid;
    s[tid] = (i < N_NODES) ? deg[i] : 0;
    __syncthreads();
    for (int off = 128; off > 0; off >>= 1) {
        if (tid < off) s[tid] += s[tid + off];
        __syncthreads();
    }
    if (tid == 0) bsum[blockIdx.x] = s[0];
}

// phase 2: exclusive scan of the SCAN_B block sums (single tiny block)
__global__ __launch_bounds__(256) void k_scan2(
    const int* __restrict__ bsum, int* __restrict__ boff)
{
    __shared__ int s[256];
    int tid = threadIdx.x;
    s[tid] = (tid < SCAN_B) ? bsum[tid] : 0;
    __syncthreads();
    for (int off = 1; off < 256; off <<= 1) {
        int u = (tid >= off) ? s[tid - off] : 0;
        __syncthreads();
        s[tid] += u;
        __syncthreads();
    }
    if (tid < SCAN_B) boff[tid] = (tid == 0) ? 0 : s[tid - 1];
}

// phase 3: in-block exclusive scan + block offset -> rowptr, cursor
__global__ __launch_bounds__(256) void k_scan3(
    const int* __restrict__ deg, const int* __restrict__ boff,
    int* __restrict__ rowptr, int* __restrict__ cursor)
{
    __shared__ int s[256];
    int tid = threadIdx.x;
    int i = blockIdx.x * 256 + tid;
    int v = (i < N_NODES) ? deg[i] : 0;
    s[tid] = v;
    __syncthreads();
    for (int off = 1; off < 256; off <<= 1) {
        int u = (tid >= off) ? s[tid - off] : 0;
        __syncthreads();
        s[tid] += u;
        __syncthreads();
    }
    int excl = s[tid] - v + boff[blockIdx.x];
    if (i < N_NODES) {
        rowptr[i] = excl;
        cursor[i] = excl;
        if (i == N_NODES - 1) rowptr[N_NODES] = excl + v;   // == N_EDGES
    }
}

__global__ __launch_bounds__(256) void k_fill(
    const int* __restrict__ src, const int* __restrict__ dst,
    int* __restrict__ cursor, int* __restrict__ eidx)
{
    int t = blockIdx.x * 256 + threadIdx.x;
    if (t >= N_EDGES) return;
    int pos = atomicAdd(&cursor[dst[t]], 1);
    eidx[pos] = src[t];
}

// ---------------------------------------------------------------------------
// Gather aggregation: out[v] = X[v] + sum_{u in N_in(v)} X[u]
// 128-dim: fp32 source (input x), fp16 output. 16 lanes/node, 8 cols each.
// ---------------------------------------------------------------------------
__global__ __launch_bounds__(256) void k_gather128(
    const float4* __restrict__ X, const int* __restrict__ rowptr,
    const int* __restrict__ eidx, f16x8* __restrict__ out)
{
    int t = blockIdx.x * 256 + threadIdx.x;
    int v = t >> 4, lane = t & 15;
    if (v >= N_NODES) return;
    int r0 = rowptr[v], r1 = rowptr[v + 1];
    float4 a0 = X[(size_t)v * 32 + lane * 2];
    float4 a1 = X[(size_t)v * 32 + lane * 2 + 1];
    for (int j = r0; j < r1; ++j) {
        int s = eidx[j];
        a0 = add4(a0, X[(size_t)s * 32 + lane * 2]);
        a1 = add4(a1, X[(size_t)s * 32 + lane * 2 + 1]);
    }
    f16x8 o;
    o[0] = (h16)a0.x; o[1] = (h16)a0.y; o[2] = (h16)a0.z; o[3] = (h16)a0.w;
    o[4] = (h16)a1.x; o[5] = (h16)a1.y; o[6] = (h16)a1.z; o[7] = (h16)a1.w;
    out[(size_t)v * 16 + lane] = o;
}

// 512-dim: fp16 src/dst, fp32 accumulate, 4-deep unrolled neighbor loop.
__global__ __launch_bounds__(256) void k_gather512h(
    const f16x8* __restrict__ X, const int* __restrict__ rowptr,
    const int* __restrict__ eidx, f16x8* __restrict__ out)
{
    int t = blockIdx.x * 256 + threadIdx.x;
    int v = t >> 6, lane = t & 63;
    if (v >= N_NODES) return;
    int r0 = rowptr[v], r1 = rowptr[v + 1];
    f16x8 sv = X[(size_t)v * 64 + lane];
    float a[8];
#pragma unroll
    for (int i = 0; i < 8; ++i) a[i] = (float)sv[i];
    int j = r0;
    for (; j + 3 < r1; j += 4) {
        int s0 = eidx[j], s1 = eidx[j + 1], s2 = eidx[j + 2], s3 = eidx[j + 3];
        f16x8 b0 = X[(size_t)s0 * 64 + lane];
        f16x8 b1 = X[(size_t)s1 * 64 + lane];
        f16x8 b2 = X[(size_t)s2 * 64 + lane];
        f16x8 b3 = X[(size_t)s3 * 64 + lane];
#pragma unroll
        for (int i = 0; i < 8; ++i)
            a[i] += ((float)b0[i] + (float)b1[i]) + ((float)b2[i] + (float)b3[i]);
    }
    for (; j < r1; ++j) {
        f16x8 b = X[(size_t)eidx[j] * 64 + lane];
#pragma unroll
        for (int i = 0; i < 8; ++i) a[i] += (float)b[i];
    }
    f16x8 o;
#pragma unroll
    for (int i = 0; i < 8; ++i) o[i] = (h16)a[i];
    out[(size_t)v * 64 + lane] = o;
}

// ---------------------------------------------------------------------------
// MFMA GEMM (fp16 A + fp16 k-major B, fp32 accum, fp16 C):
//   C[M,N] = op(A) @ B + bias
//   AFFINE: a -> relu(a*s[k]+c[k]) on A load (folded BN+ReLU)
//   RELU: epilogue relu
//   STATS: fused per-column sum / sum-of-squares of C (pre-ReLU, post-bias)
// BM=128, BN=256, BK=32. 512 threads = 8 waves (2x4), wave tile 64x64,
// 4x4 fragments of v_mfma_f32_16x16x32_f16.
// Fragment maps (gfx950, learn_hip m89-verified family):
//   A: lane l holds A[l&15][8*(l>>4)+j] ; B: lane l holds B[8*(l>>4)+j][l&15]
//   D: lane l reg r holds D[4*(l>>4)+r][l&15]
// ---------------------------------------------------------------------------
template<bool AFFINE, bool RELU, bool STATS>
__global__ __launch_bounds__(512) void k_gemm_mfma(
    const h16* __restrict__ A, const h16* __restrict__ Bt,
    const float* __restrict__ bias, const float* __restrict__ sA,
    const float* __restrict__ cA, h16* __restrict__ C,
    float* __restrict__ csum, float* __restrict__ csq,
    int M, int N, int K, int lda)
{
    __shared__ h16 As[4][128][8];   //  8 KB
    __shared__ h16 Bs[4][256][8];   // 16 KB

    const int tid  = threadIdx.x;
    const int lane = tid & 63;
    const int w    = tid >> 6;          // 0..7
    const int wr   = w >> 2;            // 0..1 (row half)
    const int wc   = w & 3;             // 0..3 (col quarter)
    const int l15  = lane & 15;
    const int lk   = lane >> 4;         // k-group 0..3
    const int m0   = blockIdx.x * 128;
    const int n0   = blockIdx.y * 256;

    // A staging: one (row, kb) 8-half chunk per thread
    const int s_row = tid >> 2;         // 0..127
    const int s_kb  = tid & 3;          // 0..3
    int ar = m0 + s_row; if (ar >= M) ar = M - 1;     // clamp; stores predicated
    const h16* aptr = A + (size_t)ar * lda + s_kb * 8;
    // B staging: two (kb, nc) chunks per thread from k-major Wt
    const int b_kb0 = tid >> 8, b_nc0 = tid & 255;          // idx = tid
    const int b_kb1 = (tid + 512) >> 8, b_nc1 = tid & 255;  // idx = tid+512

    f32x4 acc[4][4];
#pragma unroll
    for (int m = 0; m < 4; ++m)
#pragma unroll
        for (int n = 0; n < 4; ++n)
            acc[m][n] = (f32x4){0.f, 0.f, 0.f, 0.f};

    for (int k0 = 0; k0 < K; k0 += 32) {
        // ---- global loads (regs) ----
        f16x8 av = *reinterpret_cast<const f16x8*>(aptr + k0);
        if (AFFINE) {
            int kk = k0 + s_kb * 8;
            float4 s0 = *reinterpret_cast<const float4*>(&sA[kk]);
            float4 s1 = *reinterpret_cast<const float4*>(&sA[kk + 4]);
            float4 c0 = *reinterpret_cast<const float4*>(&cA[kk]);
            float4 c1 = *reinterpret_cast<const float4*>(&cA[kk + 4]);
            float va[8];
#pragma unroll
            for (int i = 0; i < 8; ++i) va[i] = (float)av[i];
            va[0] = fmaxf(fmaf(va[0], s0.x, c0.x), 0.f);
            va[1] = fmaxf(fmaf(va[1], s0.y, c0.y), 0.f);
            va[2] = fmaxf(fmaf(va[2], s0.z, c0.z), 0.f);
            va[3] = fmaxf(fmaf(va[3], s0.w, c0.w), 0.f);
            va[4] = fmaxf(fmaf(va[4], s1.x, c1.x), 0.f);
            va[5] = fmaxf(fmaf(va[5], s1.y, c1.y), 0.f);
            va[6] = fmaxf(fmaf(va[6], s1.z, c1.z), 0.f);
            va[7] = fmaxf(fmaf(va[7], s1.w, c1.w), 0.f);
#pragma unroll
            for (int i = 0; i < 8; ++i) av[i] = (h16)va[i];
        }
        f16x8 bw0 = *reinterpret_cast<const f16x8*>(
            &Bt[(size_t)(n0 + b_nc0) * K + k0 + b_kb0 * 8]);
        f16x8 bw1 = *reinterpret_cast<const f16x8*>(
            &Bt[(size_t)(n0 + b_nc1) * K + k0 + b_kb1 * 8]);

        __syncthreads();   // previous tile fully consumed
        *reinterpret_cast<f16x8*>(&As[s_kb][s_row][0]) = av;
        *reinterpret_cast<f16x8*>(&Bs[b_kb0][b_nc0][0]) = bw0;
        *reinterpret_cast<f16x8*>(&Bs[b_kb1][b_nc1][0]) = bw1;
        __syncthreads();   // tile ready

        // ---- MFMA: 16 per wave ----
        f16x8 af[4], bf[4];
#pragma unroll
        for (int m = 0; m < 4; ++m)
            af[m] = *reinterpret_cast<const f16x8*>(&As[lk][wr * 64 + m * 16 + l15][0]);
#pragma unroll
        for (int n = 0; n < 4; ++n)
            bf[n] = *reinterpret_cast<const f16x8*>(&Bs[lk][wc * 64 + n * 16 + l15][0]);
#pragma unroll
        for (int m = 0; m < 4; ++m)
#pragma unroll
            for (int n = 0; n < 4; ++n)
                acc[m][n] = __builtin_amdgcn_mfma_f32_16x16x32_f16(
                    af[m], bf[n], acc[m][n], 0, 0, 0);
    }

    // ---- epilogue (fp16 store + optional fused column stats) ----
#pragma unroll
    for (int n = 0; n < 4; ++n) {
        int col = n0 + wc * 64 + n * 16 + l15;
        float bb = bias[col];
        float sp = 0.f, qp = 0.f;
#pragma unroll
        for (int m = 0; m < 4; ++m) {
            int row0 = m0 + wr * 64 + m * 16 + lk * 4;
#pragma unroll
            for (int r = 0; r < 4; ++r) {
                int row = row0 + r;
                if (row < M) {
                    float v = acc[m][n][r] + bb;
                    if (STATS) { sp += v; qp += v * v; }
                    if (RELU) v = fmaxf(v, 0.f);
                    C[(size_t)row * N + col] = (h16)v;
                }
            }
        }
        if (STATS) {
            sp += __shfl_xor(sp, 16); qp += __shfl_xor(qp, 16);
            sp += __shfl_xor(sp, 32); qp += __shfl_xor(qp, 32);
            if (lk == 0) {
                atomicAdd(&csum[col], sp);
                atomicAdd(&csq[col], qp);
            }
        }
    }
}

// Fold BN into per-column affine: s = g*rsqrt(var+eps), c = beta - mu*s
__global__ void k_fold(const float* __restrict__ csum, const float* __restrict__ csq,
                       const float* __restrict__ g, const float* __restrict__ be,
                       float* __restrict__ sf, float* __restrict__ cf)
{
    int c = threadIdx.x;   // 512
    const float invM = 1.0f / (float)N_NODES;
    float mu  = csum[c] * invM;
    float var = csq[c] * invM - mu * mu;
    float s   = g[c] * rsqrtf(var + BN_EPS);
    sf[c] = s;
    cf[c] = be[c] - mu * s;
}

// ---------------------------------------------------------------------------
// Graph pooling (fp16 H): batch sorted -> local accumulate, boundary atomics
// ---------------------------------------------------------------------------
__global__ __launch_bounds__(256) void k_pool(
    const h16* __restrict__ H, const int* __restrict__ batch,
    float* __restrict__ pooled)
{
    __shared__ int bg[128];
    int base = blockIdx.x * 128;
    if (threadIdx.x < 128) {
        int r = base + threadIdx.x;
        bg[threadIdx.x] = (r < N_NODES) ? batch[r] : -1;
    }
    __syncthreads();
    int c0 = threadIdx.x;
    float a0 = 0.f, a1 = 0.f;
    int cur = bg[0];
    for (int r = 0; r < 128; ++r) {
        int g = bg[r];
        if (g < 0) break;
        if (g != cur) {
            atomicAdd(&pooled[cur * DIM_H + c0],       a0);
            atomicAdd(&pooled[cur * DIM_H + c0 + 256], a1);
            a0 = a1 = 0.f;
            cur = g;
        }
        size_t row = (size_t)(base + r);
        a0 += (float)H[row * DIM_H + c0];
        a1 += (float)H[row * DIM_H + c0 + 256];
    }
    if (cur >= 0) {
        atomicAdd(&pooled[cur * DIM_H + c0],       a0);
        atomicAdd(&pooled[cur * DIM_H + c0 + 256], a1);
    }
}

// head1: q[g] = relu(pooled[g] @ Wl1 + bl1)
__global__ __launch_bounds__(512) void k_head1(
    const float* __restrict__ pooled, const float* __restrict__ W,
    const float* __restrict__ b, float* __restrict__ q)
{
    __shared__ float row[DIM_H];
    int g = blockIdx.x, c = threadIdx.x;
    row[c] = pooled[(size_t)g * DIM_H + c];
    __syncthreads();
    float acc = 0.f;
    for (int k = 0; k < DIM_H; ++k)
        acc = fmaf(row[k], W[(size_t)k * DIM_H + c], acc);
    q[(size_t)g * DIM_H + c] = fmaxf(acc + b[c], 0.f);
}

// head2: out[g] = q[g] @ Wl2 + bl2
__global__ __launch_bounds__(256) void k_head2(
    const float* __restrict__ q, const float* __restrict__ W,
    const float* __restrict__ b, float* __restrict__ out)
{
    int t = blockIdx.x * 256 + threadIdx.x;
    if (t >= N_GRAPHS * DIM_OUT) return;
    int g = t / DIM_OUT, c = t % DIM_OUT;
    float acc = 0.f;
    for (int k = 0; k < DIM_H; ++k)
        acc = fmaf(q[(size_t)g * DIM_H + k], W[(size_t)k * DIM_OUT + c], acc);
    out[t] = acc + b[c];
}

// ---------------------------------------------------------------------------
extern "C" void kernel_launch(void* const* d_in, const int* in_sizes, int n_in,
                              void* d_out, int out_size, void* d_ws, size_t ws_size,
                              hipStream_t stream)
{
    const float* x   = (const float*)d_in[0];
    const int*   ei  = (const int*)d_in[1];
    const int*   src = ei;
    const int*   dst = ei + N_EDGES;
    const int*   batch = (const int*)d_in[2];
    const float* W1a = (const float*)d_in[3];
    const float* b1a = (const float*)d_in[4];
    const float* g1  = (const float*)d_in[5];
    const float* be1 = (const float*)d_in[6];
    const float* W1b = (const float*)d_in[7];
    const float* b1b = (const float*)d_in[8];
    const float* W2a = (const float*)d_in[9];
    const float* b2a = (const float*)d_in[10];
    const float* g2  = (const float*)d_in[11];
    const float* be2 = (const float*)d_in[12];
    const float* W2b = (const float*)d_in[13];
    const float* b2b = (const float*)d_in[14];
    const float* Wl1 = (const float*)d_in[15];
    const float* bl1 = (const float*)d_in[16];
    const float* Wl2 = (const float*)d_in[17];
    const float* bl2 = (const float*)d_in[18];

    char* ws = (char*)d_ws;
    const size_t ROW_H = (size_t)N_NODES * DIM_H * 2;   // 51,200,000

    if (ws_size < 110000000ull) {
        hipMemsetAsync(d_out, 0, (size_t)out_size * 4, stream);
        return;
    }
    h16* B1h = (h16*)(ws + 0);
    h16* B2h = (h16*)(ws + ROW_H);
    h16* XAh = B2h;                                   // 12.8 MB, dead after GEMM1
    char* cp  = ws + 2 * ROW_H;                       // 102,400,000
    int* deg    = (int*)(cp + 0);
    int* rowptr = (int*)(cp + 200192);
    int* cursor = (int*)(cp + 400384);
    int* eidx   = (int*)(cp + 600576);
    char* sm    = cp + 3800576;
    float* csum   = (float*)(sm + 0);
    float* csq    = (float*)(sm + 2048);
    float* sf     = (float*)(sm + 4096);
    float* cf     = (float*)(sm + 6144);
    float* pooled = (float*)(sm + 8192);
    float* qbuf   = (float*)(sm + 8192 + 131072);
    char* wt = sm + 8192 + 2 * 131072;
    h16* Wt1a = (h16*)(wt);                           // [512][128] 128 KB
    h16* Wt1b = (h16*)(wt + 131072);                  // [512][512] 512 KB
    h16* Wt2a = (h16*)(wt + 131072 + 524288);
    h16* Wt2b = (h16*)(wt + 131072 + 2 * 524288);
    int* bsum = (int*)(wt + 131072 + 3 * 524288);     // [196]
    int* boff = bsum + 256;                           // [196]

    const dim3 gemm_grid(391, 2);   // ceil(50000/128) x 512/256
    const int EB = (N_EDGES + 255) / 256;

    // ---- weight cast+transpose (once) ----
    k_wcast<<<32, 256, 0, stream>>>(W1a, Wt1a, DIM_IN, DIM_H);
    k_wcast<<<128, 256, 0, stream>>>(W1b, Wt1b, DIM_H, DIM_H);
    k_wcast<<<128, 256, 0, stream>>>(W2a, Wt2a, DIM_H, DIM_H);
    k_wcast<<<128, 256, 0, stream>>>(W2b, Wt2b, DIM_H, DIM_H);

    // ---- CSR build (counting sort by dst, hierarchical scan) ----
    hipMemsetAsync(deg, 0, (size_t)N_NODES * 4, stream);
    k_deg<<<EB, 256, 0, stream>>>(dst, deg);
    k_scan1<<<SCAN_B, 256, 0, stream>>>(deg, bsum);
    k_scan2<<<1, 256, 0, stream>>>(bsum, boff);
    k_scan3<<<SCAN_B, 256, 0, stream>>>(deg, boff, rowptr, cursor);
    k_fill<<<EB, 256, 0, stream>>>(src, dst, cursor, eidx);

    // ---- layer 1 ----
    k_gather128<<<(N_NODES * 16 + 255) / 256, 256, 0, stream>>>(
        (const float4*)x, rowptr, eidx, (f16x8*)XAh);
    hipMemsetAsync(csum, 0, 4096, stream);
    k_gemm_mfma<false, false, true><<<gemm_grid, 512, 0, stream>>>(
        XAh, Wt1a, b1a, nullptr, nullptr, B1h, csum, csq,
        N_NODES, DIM_H, DIM_IN, DIM_IN);
    k_fold<<<1, 512, 0, stream>>>(csum, csq, g1, be1, sf, cf);
    k_gemm_mfma<true, true, false><<<gemm_grid, 512, 0, stream>>>(
        B1h, Wt1b, b1b, sf, cf, B2h, nullptr, nullptr,
        N_NODES, DIM_H, DIM_H, DIM_H);

    // ---- layer 2 ----
    k_gather512h<<<(N_NODES * 64) / 256, 256, 0, stream>>>(
        (const f16x8*)B2h, rowptr, eidx, (f16x8*)B1h);
    hipMemsetAsync(csum, 0, 4096, stream);
    k_gemm_mfma<false, false, true><<<gemm_grid, 512, 0, stream>>>(
        B1h, Wt2a, b2a, nullptr, nullptr, B2h, csum, csq,
        N_NODES, DIM_H, DIM_H, DIM_H);
    k_fold<<<1, 512, 0, stream>>>(csum, csq, g2, be2, sf, cf);
    k_gemm_mfma<true, true, false><<<gemm_grid, 512, 0, stream>>>(
        B2h, Wt2b, b2b, sf, cf, B1h, nullptr, nullptr,
        N_NODES, DIM_H, DIM_H, DIM_H);

    // ---- pool + head ----
    hipMemsetAsync(pooled, 0, (size_t)N_GRAPHS * DIM_H * 4, stream);
    k_pool<<<(N_NODES + 127) / 128, 256, 0, stream>>>(B1h, batch, pooled);
    k_head1<<<N_GRAPHS, 512, 0, stream>>>(pooled, Wl1, bl1, qbuf);
    k_head2<<<3, 256, 0, stream>>>(qbuf, Wl2, bl2, (float*)d_out);
}